// Round 1
// 5630.199 us; speedup vs baseline: 1.0152x; 1.0152x over previous
//
#include <hip/hip_runtime.h>

// ---------------------------------------------------------------------------
// BasicModel_43387759624704: 2-layer GRU (T=512, B=256, H=512, COV=128),
// ragged masking, covariate head, exp(-dist) head. Inputs/outputs FLOAT32;
// MFMA operands bf16 in workspace, f32 accumulate/state.
//
// ROUND 8: attack the ~4.4 ms of non-scan GEMM work.
//  * gemm_bias: m97-style staging -- __builtin_amdgcn_global_load_lds width=16
//    into LINEAR LDS, with the XOR chunk-swizzle applied on the GLOBAL source
//    address (rule 21: linear dest + inverse-swizzled source + swizzled
//    ds_read). Removes the VGPR roundtrip + VALU address calc (ladder: +69%).
//  * preds: rebuilt as the same 128x128 GEMM structure (N=128, 1 col block)
//    with mask/time epilogue fused; replaces the 64-row, W_cov-reloading
//    structure.
//  * cvt_pad_x: constant-divisor (129->192) specialization -> magic multiply.
//  * scan_gru: UNCHANGED (round-7 fence-free barrier protocol).
// ---------------------------------------------------------------------------

typedef unsigned short u16;
typedef unsigned long long u64;
typedef __attribute__((ext_vector_type(8))) short short8;
typedef short8 bf16x8;
typedef __attribute__((ext_vector_type(4))) float f32x4;

#define T_DIM 512
#define B_DIM 256
#define H_DIM 512
#define G3H   1536
#define BT    131072        // 256*512
#define XPK   192           // padded K for layer-0 input GEMM (129 -> 192)
#define PRED_ELEMS 16875264 // 256*511*129

// async global->LDS, 16B per lane, wave-uniform LDS base (HW: base + lane*16)
#define GLD16(gp, lp) __builtin_amdgcn_global_load_lds( \
    (const __attribute__((address_space(1))) void*)(gp), \
    (__attribute__((address_space(3))) void*)(lp), 16, 0, 0)

__device__ __forceinline__ u16 f2bf(float f) {  // RNE
    union { float f; unsigned i; } v; v.f = f;
    unsigned i = v.i;
    return (u16)((i + 0x7FFFu + ((i >> 16) & 1u)) >> 16);
}
__device__ __forceinline__ float bf2f(u16 u) {
    union { unsigned i; float f; } v; v.i = ((unsigned)u) << 16; return v.f;
}
__device__ __forceinline__ float sigm(float x) { return 1.f / (1.f + __expf(-x)); }
__device__ __forceinline__ float tanh_f(float x) {
    float ax = fabsf(x);
    float e = __expf(-2.f * ax);
    float t = (1.f - e) / (1.f + e);
    return x < 0.f ? -t : t;
}
// coherent 16B load (2x relaxed agent atomics: global_load sc0 sc1, no inv)
__device__ __forceinline__ bf16x8 aload16(const u16* p) {
    union { bf16x8 v; u64 q[2]; } r;
    const u64* qp = (const u64*)p;
    r.q[0] = __hip_atomic_load(qp + 0, __ATOMIC_RELAXED, __HIP_MEMORY_SCOPE_AGENT);
    r.q[1] = __hip_atomic_load(qp + 1, __ATOMIC_RELAXED, __HIP_MEMORY_SCOPE_AGENT);
    return r.v;
}

// ---------------------------------------------------------------------------
__global__ void zero_ctr_kernel(unsigned* ctr) {
    for (int i = threadIdx.x; i < 2048; i += 256) ctr[i] = 0u;
}

// f32 [rows][srcK] -> bf16 [rows][dstK] (zero-pad cols >= srcK) -- weights
__global__ void cvt_pad_kernel(const float* __restrict__ src, u16* __restrict__ dst,
                               int rows, int srcK, int dstK) {
    int n = rows * dstK;
    for (int idx = blockIdx.x * blockDim.x + threadIdx.x; idx < n;
         idx += gridDim.x * blockDim.x) {
        int row = idx / dstK, col = idx - row * dstK;
        float v = (col < srcK) ? src[(size_t)row * srcK + col] : 0.f;
        dst[idx] = f2bf(v);
    }
}

// specialization for x: 129 -> 192, compile-time divisor (magic multiply)
__global__ void cvt_pad_x_kernel(const float* __restrict__ src,
                                 u16* __restrict__ dst, int rows) {
    const int n = rows * 192;
    for (int idx = blockIdx.x * blockDim.x + threadIdx.x; idx < n;
         idx += gridDim.x * blockDim.x) {
        const int row = idx / 192, col = idx - row * 192;
        float v = (col < 129) ? src[(size_t)row * 129 + col] : 0.f;
        dst[idx] = f2bf(v);
    }
}

// W_cov f32 [128][513] -> bf16 [128][512] + f32 wlast[128] (col 512)
__global__ void cvt_wcov_kernel(const float* __restrict__ Wcov,
                                u16* __restrict__ WcovBf, float* __restrict__ wlastf) {
    int idx0 = blockIdx.x * blockDim.x + threadIdx.x;
    for (int idx = idx0; idx < 128 * 512; idx += gridDim.x * blockDim.x) {
        int row = idx >> 9, col = idx & 511;
        WcovBf[idx] = f2bf(Wcov[row * 513 + col]);
    }
    if (idx0 < 128) wlastf[idx0] = Wcov[idx0 * 513 + 512];
}

// ---------------------------------------------------------------------------
// C[m][n] = sum_k A[m][k]*B[n][k] + bias[n]; A,B bf16 K-major; bias f32; C bf16
// m97 structure: global_load_lds dwordx4 staging, linear [128][64] LDS tiles,
// source-side XOR chunk swizzle (chunk ^= row&7 within each 128B row) so the
// ds_read_b128 fragment reads are 2-way-per-phase conflict free.
__global__ __launch_bounds__(256) void gemm_bias_kernel(
    const u16* __restrict__ A, int lda, const u16* __restrict__ B, int ldb,
    const float* __restrict__ bias, u16* __restrict__ C, int ldc, int K) {
    __shared__ __attribute__((aligned(16))) u16 Ash[128 * 64];
    __shared__ __attribute__((aligned(16))) u16 Bsh[128 * 64];
    const int tid = threadIdx.x, lane = tid & 63, w = tid >> 6;
    const int m0 = blockIdx.y * 128, n0 = blockIdx.x * 128;
    const int r0 = (w & 1) * 64, c0 = (w >> 1) * 64;
    const int am = lane & 15, aq = lane >> 4;
    const int l8 = lane >> 3, lc = lane & 7;
    const int swz = (lc ^ l8) << 3;   // source-side swizzled k-chunk (elems)
    f32x4 acc[4][4] = {};
    for (int kt = 0; kt < K; kt += 64) {
        __syncthreads();              // prev tile's MFMA reads done
#pragma unroll
        for (int s = 0; s < 4; ++s) {
            const int i = w * 4 + s;         // 1KB wave-load index, rows i*8..i*8+7
            const int row = i * 8 + l8;
            GLD16(A + (size_t)(m0 + row) * lda + kt + swz, &Ash[i * 512]);
            GLD16(B + (size_t)(n0 + row) * ldb + kt + swz, &Bsh[i * 512]);
        }
        __syncthreads();              // vmcnt(0) drain: tiles landed
#pragma unroll
        for (int ks = 0; ks < 2; ++ks) {
            bf16x8 a[4], bb[4];
#pragma unroll
            for (int f = 0; f < 4; ++f) {
                const int ar = r0 + f * 16 + am;
                a[f] = *(short8*)&Ash[ar * 64 + (((ks * 4 + aq) ^ (ar & 7)) << 3)];
            }
#pragma unroll
            for (int f = 0; f < 4; ++f) {
                const int br = c0 + f * 16 + am;
                bb[f] = *(short8*)&Bsh[br * 64 + (((ks * 4 + aq) ^ (br & 7)) << 3)];
            }
#pragma unroll
            for (int fi = 0; fi < 4; ++fi)
#pragma unroll
                for (int fj = 0; fj < 4; ++fj)
                    acc[fi][fj] = __builtin_amdgcn_mfma_f32_16x16x32_bf16(
                        a[fi], bb[fj], acc[fi][fj], 0, 0, 0);
        }
    }
#pragma unroll
    for (int fj = 0; fj < 4; ++fj) {
        const int col = n0 + c0 + fj * 16 + am;
        const float bia = bias[col];
#pragma unroll
        for (int fi = 0; fi < 4; ++fi) {
#pragma unroll
            for (int r = 0; r < 4; ++r) {
                const int row = m0 + r0 + fi * 16 + aq * 4 + r;
                C[(size_t)row * ldc + col] = f2bf(acc[fi][fj][r] + bia);
            }
        }
    }
}

// ---------------------------------------------------------------------------
// Persistent GRU scan over one time chunk. Grid (32 col-blocks, 16 row-groups)
// = 512 blocks = exactly 2/CU. Whh slice LDS-resident for all TC steps.
// Fence-free barrier: wave 0 publishes the block's 16x16 h patch as 64 u64
// RELAXED agent atomics (write-through to MALL), drains with raw
// s_waitcnt vmcnt(0), then lane 0 RELAXED-adds the row-group counter and
// spins RELAXED. No buffer_wbl2 / buffer_inv anywhere in the loop.
__global__ __launch_bounds__(256, 2) void scan_gru_kernel(
    const u16* __restrict__ gi,      // [TC][256][1536] chunk (bf16)
    const u16* __restrict__ Whh,     // [1536][512] bf16
    const float* __restrict__ bhh,   // [1536] f32
    const int* __restrict__ lengths, // [256]
    const float* __restrict__ h0l,   // [256][512] f32 (layer slice)
    const u16* __restrict__ h0bfl,   // [256][512] bf16 (layer slice)
    u16* __restrict__ o,             // [TC][256][512] chunk (bf16)
    u16* __restrict__ hbf,           // [2][256][512] bf16 state (parity by t)
    float* __restrict__ hlast,       // [256][512] f32 carry (layer slice)
    unsigned* __restrict__ ctr,      // 16 counters, stride 64 uints
    int t0, int TC, unsigned base) {
    __shared__ __attribute__((aligned(16))) u16 Wl[48 * 520];
    __shared__ __attribute__((aligned(16))) float P[4 * 3 * 256];
    __shared__ __attribute__((aligned(16))) float bhhf[48];
    __shared__ __attribute__((aligned(8)))  u16 hX[256];
    const int tid = threadIdx.x, lane = tid & 63, w = tid >> 6;
    const int n0 = blockIdx.x * 16, b0 = blockIdx.y * 16;
    // one-time: stage Whh slice into LDS (rows: 3 gates x 16 cols, K=512)
#pragma unroll
    for (int it = 0; it < 12; ++it) {
        int f = it * 2048 + tid * 8;
        int j = f >> 9, k = f & 511;
        *(short8*)&Wl[j * 520 + k] =
            *(const short8*)(Whh + ((size_t)((j >> 4) * 512 + n0 + (j & 15))) * 512 + k);
    }
    if (tid < 48) bhhf[tid] = bhh[(tid >> 4) * 512 + n0 + (tid & 15)];
    const int m = tid >> 4, c = tid & 15;
    const int b = b0 + m, col = n0 + c;
    float h = (t0 == 0) ? h0l[(size_t)b * 512 + col]
                        : hlast[(size_t)b * 512 + col];
    const int len = lengths[b];
    const int am = lane & 15, aq = lane >> 4;
    unsigned* myctr = ctr + blockIdx.y * 64;
    // preload step-0 gi into registers
    size_t gib = (size_t)b * (size_t)G3H + n0 + c;
    float gr = bf2f(gi[gib]), gz = bf2f(gi[gib + 512]), gn = bf2f(gi[gib + 1024]);
    __syncthreads();
    for (int tl = 0; tl < TC; ++tl) {
        const int t = t0 + tl;
        const u16* Asrc = (t == 0) ? h0bfl : (hbf + (size_t)((t - 1) & 1) * BT);
        f32x4 ar = {}, az = {}, an = {};
#pragma unroll
        for (int kb = 0; kb < 4; ++kb) {
            const int k = w * 128 + kb * 32 + aq * 8;
            bf16x8 a = aload16(Asrc + (size_t)(b0 + am) * 512 + k);  // MALL-fresh
            bf16x8 wr = *(short8*)&Wl[(0 + am) * 520 + k];
            bf16x8 wz = *(short8*)&Wl[(16 + am) * 520 + k];
            bf16x8 wn = *(short8*)&Wl[(32 + am) * 520 + k];
            ar = __builtin_amdgcn_mfma_f32_16x16x32_bf16(a, wr, ar, 0, 0, 0);
            az = __builtin_amdgcn_mfma_f32_16x16x32_bf16(a, wz, az, 0, 0, 0);
            an = __builtin_amdgcn_mfma_f32_16x16x32_bf16(a, wn, an, 0, 0, 0);
        }
#pragma unroll
        for (int r = 0; r < 4; ++r) {
            P[(w * 3 + 0) * 256 + (aq * 4 + r) * 16 + am] = ar[r];
            P[(w * 3 + 1) * 256 + (aq * 4 + r) * 16 + am] = az[r];
            P[(w * 3 + 2) * 256 + (aq * 4 + r) * 16 + am] = an[r];
        }
        __syncthreads();
        float Cr = bhhf[c], Cz = bhhf[16 + c], Cn = bhhf[32 + c];
#pragma unroll
        for (int w2 = 0; w2 < 4; ++w2) {
            Cr += P[(w2 * 3 + 0) * 256 + tid];
            Cz += P[(w2 * 3 + 1) * 256 + tid];
            Cn += P[(w2 * 3 + 2) * 256 + tid];
        }
        float r_ = sigm(gr + Cr);
        float z_ = sigm(gz + Cz);
        float n_ = tanh_f(gn + r_ * Cn);
        float hnew = (1.f - z_) * n_ + z_ * h;
        bool valid = t < len;
        h = valid ? hnew : h;
        o[((size_t)tl * 256 + b) * 512 + col] = f2bf(valid ? hnew : 0.f);
        if (tl < TC - 1) {
            hX[tid] = f2bf(h);  // stage patch for wide publish
            // prefetch next step's gi (independent of the barrier)
            const size_t gib2 = ((size_t)(tl + 1) * 256 + b) * (size_t)G3H + n0 + c;
            gr = bf2f(gi[gib2]); gz = bf2f(gi[gib2 + 512]); gn = bf2f(gi[gib2 + 1024]);
            __syncthreads();  // hX ready; P consumed
            if (w == 0) {
                const int row = lane >> 2, cg = (lane & 3) * 4;
                union { u64 q; u16 s[4]; } pk;
                pk.s[0] = hX[row * 16 + cg + 0];
                pk.s[1] = hX[row * 16 + cg + 1];
                pk.s[2] = hX[row * 16 + cg + 2];
                pk.s[3] = hX[row * 16 + cg + 3];
                __hip_atomic_store(
                    (u64*)(hbf + (size_t)(t & 1) * BT + (size_t)(b0 + row) * 512 + n0 + cg),
                    pk.q, __ATOMIC_RELAXED, __HIP_MEMORY_SCOPE_AGENT);
                // order h stores before the counter add (wave-local drain; no cache ops)
                asm volatile("s_waitcnt vmcnt(0)" ::: "memory");
                if (lane == 0) {
                    __hip_atomic_fetch_add(myctr, 1u, __ATOMIC_RELAXED,
                                           __HIP_MEMORY_SCOPE_AGENT);
                    const unsigned tgt = base + (unsigned)(tl + 1) * 32u;
                    while (__hip_atomic_load(myctr, __ATOMIC_RELAXED,
                                             __HIP_MEMORY_SCOPE_AGENT) < tgt)
                        __builtin_amdgcn_s_sleep(2);
                }
            }
            __syncthreads();
        } else {
            // chunk's last step: next consumer is the next kernel launch
            // (stream order + end-of-kernel writeback) -> plain stores suffice
            hbf[(size_t)(t & 1) * BT + (size_t)b * 512 + col] = f2bf(h);
            hlast[(size_t)b * 512 + col] = h;
        }
    }
}

// ---------------------------------------------------------------------------
// preds as a 128x128 GEMM (N=128 -> one col-block) with fused epilogue:
// rows r = tl*256 + b over the chunk; out[b][t][c] = mask * (acc + b_cov[c]
// + x[t,b,0]*wlast[c]); channel 128 zeroed. Same staging as gemm_bias.
__global__ __launch_bounds__(256) void preds_kernel(
    const u16* __restrict__ o1c, const u16* __restrict__ WcovBf,
    const float* __restrict__ wlastf, const float* __restrict__ bcov,
    const float* __restrict__ x, const int* __restrict__ lengths,
    float* __restrict__ out, int t0) {
    __shared__ __attribute__((aligned(16))) u16 Ash[128 * 64];
    __shared__ __attribute__((aligned(16))) u16 Bsh[128 * 64];
    const int tid = threadIdx.x, lane = tid & 63, w = tid >> 6;
    const int m0 = blockIdx.x * 128;
    const int r0 = (w & 1) * 64, c0 = (w >> 1) * 64;
    const int am = lane & 15, aq = lane >> 4;
    const int l8 = lane >> 3, lc = lane & 7;
    const int swz = (lc ^ l8) << 3;
    f32x4 acc[4][4] = {};
    for (int kt = 0; kt < 512; kt += 64) {
        __syncthreads();
#pragma unroll
        for (int s = 0; s < 4; ++s) {
            const int i = w * 4 + s;
            const int row = i * 8 + l8;
            GLD16(o1c + (size_t)(m0 + row) * 512 + kt + swz, &Ash[i * 512]);
            GLD16(WcovBf + (size_t)row * 512 + kt + swz, &Bsh[i * 512]);
        }
        __syncthreads();
#pragma unroll
        for (int ks = 0; ks < 2; ++ks) {
            bf16x8 a[4], bb[4];
#pragma unroll
            for (int f = 0; f < 4; ++f) {
                const int ar2 = r0 + f * 16 + am;
                a[f] = *(short8*)&Ash[ar2 * 64 + (((ks * 4 + aq) ^ (ar2 & 7)) << 3)];
            }
#pragma unroll
            for (int f = 0; f < 4; ++f) {
                const int br = c0 + f * 16 + am;
                bb[f] = *(short8*)&Bsh[br * 64 + (((ks * 4 + aq) ^ (br & 7)) << 3)];
            }
#pragma unroll
            for (int fi = 0; fi < 4; ++fi)
#pragma unroll
                for (int fj = 0; fj < 4; ++fj)
                    acc[fi][fj] = __builtin_amdgcn_mfma_f32_16x16x32_bf16(
                        a[fi], bb[fj], acc[fi][fj], 0, 0, 0);
        }
    }
    const int tl = m0 >> 8;     // one tl per block (128 rows = half of a tl)
    const int t = t0 + tl;
    if (t < 511) {
#pragma unroll
        for (int fj = 0; fj < 4; ++fj) {
            const int cc = c0 + fj * 16 + am;
            const float bc = bcov[cc], wl = wlastf[cc];
#pragma unroll
            for (int fi = 0; fi < 4; ++fi) {
#pragma unroll
                for (int r = 0; r < 4; ++r) {
                    const int row = m0 + r0 + fi * 16 + aq * 4 + r;
                    const int b = row & 255;
                    const bool valid = t < lengths[b] - 1;
                    const float tim = x[(size_t)t * (256 * 129) + b * 129];
                    out[(size_t)b * (511 * 129) + (size_t)t * 129 + cc] =
                        valid ? acc[fi][fj][r] + bc + tim * wl : 0.f;
                }
            }
        }
        if (tid < 128)  // channel 128 is always zero
            out[(size_t)((m0 & 255) + tid) * (511 * 129) + (size_t)t * 129 + 128] = 0.f;
    }
}

// ---------------------------------------------------------------------------
// dist[i][p] = exp(-(last_flat[i] @ W_par[p] + b_par[p])), f32 out.
__global__ void dist_kernel(const float* __restrict__ hl0,
                            const float* __restrict__ hl1,
                            const float* __restrict__ Wpar,
                            const float* __restrict__ bpar, float* __restrict__ out) {
    const int w = threadIdx.x >> 6, lane = threadIdx.x & 63;
    const float bp0 = bpar[0], bp1 = bpar[1];
    for (int rr = 0; rr < 8; ++rr) {
        const int i = (blockIdx.x * 4 + w) * 8 + rr;
        const int l = i >> 7, bb = (2 * i) & 255;
        const float* base = (l ? hl1 : hl0) + (size_t)bb * 512;
        float a0 = 0.f, a1 = 0.f;
#pragma unroll
        for (int cc = 0; cc < 16; ++cc) {
            const int k = cc * 64 + lane;
            const float v = base[k];
            a0 += v * Wpar[k];
            a1 += v * Wpar[1024 + k];
        }
#pragma unroll
        for (int off = 32; off; off >>= 1) {
            a0 += __shfl_down(a0, off);
            a1 += __shfl_down(a1, off);
        }
        if (lane == 0) {
            out[PRED_ELEMS + i * 2 + 0] = __expf(-(a0 + bp0));
            out[PRED_ELEMS + i * 2 + 1] = __expf(-(a1 + bp1));
        }
    }
}

// ---------------------------------------------------------------------------
extern "C" void kernel_launch(void* const* d_in, const int* in_sizes, int n_in,
                              void* d_out, int out_size, void* d_ws, size_t ws_size,
                              hipStream_t stream) {
    const float* x    = (const float*)d_in[0];
    const int* lens   = (const int*)d_in[1];
    const float* h0   = (const float*)d_in[2];
    const float* Wih0 = (const float*)d_in[3];
    const float* Whh0 = (const float*)d_in[4];
    const float* bih0 = (const float*)d_in[5];
    const float* bhh0 = (const float*)d_in[6];
    const float* Wih1 = (const float*)d_in[7];
    const float* Whh1 = (const float*)d_in[8];
    const float* bih1 = (const float*)d_in[9];
    const float* bhh1 = (const float*)d_in[10];
    const float* Wcov = (const float*)d_in[11];
    const float* bcov = (const float*)d_in[12];
    const float* Wpar = (const float*)d_in[13];
    const float* bpar = (const float*)d_in[14];
    float* out = (float*)d_out;
    char* wsb = (char*)d_ws;

    size_t off = 0;
    auto take = [&](size_t bytes) -> size_t {
        size_t r = off; off += (bytes + 255) & ~(size_t)255; return r;
    };
    const size_t oCtr   = take(8192);                   // 2 layers x 16 ctrs
    const size_t oHl0   = take((size_t)BT * 4);         // layer0 f32 carry
    const size_t oHl1   = take((size_t)BT * 4);         // layer1 f32 carry
    const size_t oHbf0  = take((size_t)2 * BT * 2);     // layer0 bf16 parity
    const size_t oHbf1  = take((size_t)2 * BT * 2);     // layer1 bf16 parity
    const size_t oH0bf  = take((size_t)2 * BT * 2);     // bf16(h0) both layers
    const size_t oWih0b = take((size_t)G3H * XPK * 2);
    const size_t oWih1b = take((size_t)G3H * 512 * 2);
    const size_t oWhh0b = take((size_t)G3H * 512 * 2);
    const size_t oWhh1b = take((size_t)G3H * 512 * 2);
    const size_t oWcovb = take((size_t)128 * 512 * 2);
    const size_t oWlast = take(512);
    const size_t fixed = off;

    const size_t per = (size_t)256 * XPK * 2 + (size_t)256 * G3H * 2 +
                       2 * (size_t)256 * 512 * 2 + 2048;
    const size_t remain = ws_size > fixed ? ws_size - fixed : 0;
    int TC = 1;
    const int cands[10] = {512, 256, 128, 64, 32, 16, 8, 4, 2, 1};
    for (int i = 0; i < 10; ++i)
        if ((size_t)cands[i] * per <= remain) { TC = cands[i]; break; }

    const size_t oXbf = take((size_t)TC * 256 * XPK * 2);
    const size_t oGi  = take((size_t)TC * 256 * G3H * 2);
    const size_t oO0  = take((size_t)TC * 256 * 512 * 2);
    const size_t oO1  = take((size_t)TC * 256 * 512 * 2);

    unsigned* ctr = (unsigned*)(wsb + oCtr);
    float* hl0  = (float*)(wsb + oHl0);
    float* hl1  = (float*)(wsb + oHl1);
    u16* hbf0   = (u16*)(wsb + oHbf0);
    u16* hbf1   = (u16*)(wsb + oHbf1);
    u16* h0bf   = (u16*)(wsb + oH0bf);
    u16* wih0b  = (u16*)(wsb + oWih0b);
    u16* wih1b  = (u16*)(wsb + oWih1b);
    u16* whh0b  = (u16*)(wsb + oWhh0b);
    u16* whh1b  = (u16*)(wsb + oWhh1b);
    u16* wcovb  = (u16*)(wsb + oWcovb);
    float* wlastf = (float*)(wsb + oWlast);
    u16* xbfc   = (u16*)(wsb + oXbf);
    u16* gic    = (u16*)(wsb + oGi);
    u16* o0c    = (u16*)(wsb + oO0);
    u16* o1c    = (u16*)(wsb + oO1);

    zero_ctr_kernel<<<1, 256, 0, stream>>>(ctr);
    cvt_pad_kernel<<<288, 256, 0, stream>>>(Wih0, wih0b, G3H, 129, XPK);
    cvt_pad_kernel<<<768, 256, 0, stream>>>(Wih1, wih1b, G3H, 512, 512);
    cvt_pad_kernel<<<768, 256, 0, stream>>>(Whh0, whh0b, G3H, 512, 512);
    cvt_pad_kernel<<<768, 256, 0, stream>>>(Whh1, whh1b, G3H, 512, 512);
    cvt_pad_kernel<<<256, 256, 0, stream>>>(h0, h0bf, 512, 512, 512);
    cvt_wcov_kernel<<<64, 256, 0, stream>>>(Wcov, wcovb, wlastf);

    unsigned base = 0;
    for (int t0 = 0; t0 < T_DIM; t0 += TC) {
        int n = TC * 256 * XPK;
        int pg = (n + 255) / 256; if (pg > 2048) pg = 2048;
        cvt_pad_x_kernel<<<pg, 256, 0, stream>>>(
            x + (size_t)t0 * 256 * 129, xbfc, TC * 256);
        gemm_bias_kernel<<<dim3(12, TC * 2), 256, 0, stream>>>(
            xbfc, XPK, wih0b, XPK, bih0, gic, G3H, XPK);
        scan_gru_kernel<<<dim3(32, 16), 256, 0, stream>>>(
            gic, whh0b, bhh0, lens, h0, h0bf, o0c, hbf0, hl0,
            ctr, t0, TC, base);
        gemm_bias_kernel<<<dim3(12, TC * 2), 256, 0, stream>>>(
            o0c, H_DIM, wih1b, H_DIM, bih1, gic, G3H, H_DIM);
        scan_gru_kernel<<<dim3(32, 16), 256, 0, stream>>>(
            gic, whh1b, bhh1, lens, h0 + (size_t)BT, h0bf + (size_t)BT,
            o1c, hbf1, hl1, ctr + 1024, t0, TC, base);
        preds_kernel<<<dim3(TC * 2), 256, 0, stream>>>(
            o1c, wcovb, wlastf, bcov, x, lens, out, t0);
        base += (unsigned)(TC - 1) * 32u;
    }
    dist_kernel<<<8, 256, 0, stream>>>(hl0, hl1, Wpar, bpar, out);
}

// Round 2
// 5363.600 us; speedup vs baseline: 1.0656x; 1.0497x over previous
//
#include <hip/hip_runtime.h>

// ---------------------------------------------------------------------------
// BasicModel_43387759624704: 2-layer GRU (T=512, B=256, H=512, COV=128),
// ragged masking, covariate head, exp(-dist) head. Inputs/outputs FLOAT32;
// MFMA operands bf16 in workspace, f32 accumulate/state.
//
// ROUND 9:
//  * scan_gru: per-colblock FLAG barrier replaces the shared atomic counter.
//    Each wave shuffle-packs and publishes its own 4 h-rows (16 u64 stores),
//    __syncthreads drains all waves' stores (compiler emits vmcnt(0) before
//    s_barrier), tid0 stores flag = step#. Consumers poll only their 8
//    producer flags right before the aload16s. Removes the RMW serialization,
//    lane0 spin + broadcast barrier, and the hX LDS roundtrip.
//  * gemm_bias: epilogue repacks C through the reused 32KB staging LDS and
//    stores short8 (1KB/wave/instr) instead of 64 scalar 2B stores/thread.
//  * prep_kernel: fuses ctr-zero + all weight/h0/Wcov conversions (7 -> 1
//    dispatch).
// ---------------------------------------------------------------------------

typedef unsigned short u16;
typedef unsigned long long u64;
typedef __attribute__((ext_vector_type(8))) short short8;
typedef short8 bf16x8;
typedef __attribute__((ext_vector_type(4))) float f32x4;

#define T_DIM 512
#define B_DIM 256
#define H_DIM 512
#define G3H   1536
#define BT    131072        // 256*512
#define XPK   192           // padded K for layer-0 input GEMM (129 -> 192)
#define PRED_ELEMS 16875264 // 256*511*129

// async global->LDS, 16B per lane, wave-uniform LDS base (HW: base + lane*16)
#define GLD16(gp, lp) __builtin_amdgcn_global_load_lds( \
    (const __attribute__((address_space(1))) void*)(gp), \
    (__attribute__((address_space(3))) void*)(lp), 16, 0, 0)

__device__ __forceinline__ u16 f2bf(float f) {  // RNE
    union { float f; unsigned i; } v; v.f = f;
    unsigned i = v.i;
    return (u16)((i + 0x7FFFu + ((i >> 16) & 1u)) >> 16);
}
__device__ __forceinline__ float bf2f(u16 u) {
    union { unsigned i; float f; } v; v.i = ((unsigned)u) << 16; return v.f;
}
__device__ __forceinline__ float sigm(float x) { return 1.f / (1.f + __expf(-x)); }
__device__ __forceinline__ float tanh_f(float x) {
    float ax = fabsf(x);
    float e = __expf(-2.f * ax);
    float t = (1.f - e) / (1.f + e);
    return x < 0.f ? -t : t;
}
// coherent 16B load (2x relaxed agent atomics: global_load sc0 sc1, no inv)
__device__ __forceinline__ bf16x8 aload16(const u16* p) {
    union { bf16x8 v; u64 q[2]; } r;
    const u64* qp = (const u64*)p;
    r.q[0] = __hip_atomic_load(qp + 0, __ATOMIC_RELAXED, __HIP_MEMORY_SCOPE_AGENT);
    r.q[1] = __hip_atomic_load(qp + 1, __ATOMIC_RELAXED, __HIP_MEMORY_SCOPE_AGENT);
    return r.v;
}

// ---------------------------------------------------------------------------
// One-dispatch preamble: ctr zero + all weight conversions.
__global__ void prep_kernel(const float* __restrict__ Wih0, const float* __restrict__ Wih1,
                            const float* __restrict__ Whh0, const float* __restrict__ Whh1,
                            const float* __restrict__ h0,   const float* __restrict__ Wcov,
                            u16* __restrict__ wih0b, u16* __restrict__ wih1b,
                            u16* __restrict__ whh0b, u16* __restrict__ whh1b,
                            u16* __restrict__ h0bf,  u16* __restrict__ wcovb,
                            float* __restrict__ wlastf, unsigned* __restrict__ ctr) {
    const int gid = blockIdx.x * 256 + threadIdx.x;
    const int gsz = gridDim.x * 256;
    for (int i = gid; i < 2048; i += gsz) ctr[i] = 0u;
    for (int i = gid; i < 128; i += gsz) wlastf[i] = Wcov[i * 513 + 512];
    for (int i = gid; i < 128 * 512; i += gsz) {
        int r = i >> 9, c = i & 511;
        wcovb[i] = f2bf(Wcov[r * 513 + c]);
    }
    for (int i = gid; i < 512 * 512; i += gsz) h0bf[i] = f2bf(h0[i]);
    for (int i = gid; i < 1536 * 192; i += gsz) {
        int r = i / 192, c = i - r * 192;
        wih0b[i] = f2bf(c < 129 ? Wih0[r * 129 + c] : 0.f);
    }
    for (int i = gid; i < 1536 * 512; i += gsz) wih1b[i] = f2bf(Wih1[i]);
    for (int i = gid; i < 1536 * 512; i += gsz) whh0b[i] = f2bf(Whh0[i]);
    for (int i = gid; i < 1536 * 512; i += gsz) whh1b[i] = f2bf(Whh1[i]);
}

// specialization for x: 129 -> 192, compile-time divisor (magic multiply)
__global__ void cvt_pad_x_kernel(const float* __restrict__ src,
                                 u16* __restrict__ dst, int rows) {
    const int n = rows * 192;
    for (int idx = blockIdx.x * blockDim.x + threadIdx.x; idx < n;
         idx += gridDim.x * blockDim.x) {
        const int row = idx / 192, col = idx - row * 192;
        float v = (col < 129) ? src[(size_t)row * 129 + col] : 0.f;
        dst[idx] = f2bf(v);
    }
}

// ---------------------------------------------------------------------------
// C[m][n] = sum_k A[m][k]*B[n][k] + bias[n]; A,B bf16 K-major; bias f32; C bf16
// m97 staging (global_load_lds dwordx4, source-side XOR chunk swizzle) +
// LDS-repacked coalesced C writeback (reuses the 32KB staging buffer).
__global__ __launch_bounds__(256) void gemm_bias_kernel(
    const u16* __restrict__ A, int lda, const u16* __restrict__ B, int ldb,
    const float* __restrict__ bias, u16* __restrict__ C, int ldc, int K) {
    __shared__ __attribute__((aligned(16))) u16 Sh[16384];   // A:0..8191 B:8192..16383
    u16* Ash = Sh;
    u16* Bsh = Sh + 8192;
    const int tid = threadIdx.x, lane = tid & 63, w = tid >> 6;
    const int m0 = blockIdx.y * 128, n0 = blockIdx.x * 128;
    const int r0 = (w & 1) * 64, c0 = (w >> 1) * 64;
    const int am = lane & 15, aq = lane >> 4;
    const int l8 = lane >> 3, lc = lane & 7;
    const int swz = (lc ^ l8) << 3;   // source-side swizzled k-chunk (elems)
    f32x4 acc[4][4] = {};
    for (int kt = 0; kt < K; kt += 64) {
        __syncthreads();              // prev tile's MFMA reads done
#pragma unroll
        for (int s = 0; s < 4; ++s) {
            const int i = w * 4 + s;         // 1KB wave-load index, rows i*8..i*8+7
            const int row = i * 8 + l8;
            GLD16(A + (size_t)(m0 + row) * lda + kt + swz, &Ash[i * 512]);
            GLD16(B + (size_t)(n0 + row) * ldb + kt + swz, &Bsh[i * 512]);
        }
        __syncthreads();              // vmcnt(0) drain: tiles landed
#pragma unroll
        for (int ks = 0; ks < 2; ++ks) {
            bf16x8 a[4], bb[4];
#pragma unroll
            for (int f = 0; f < 4; ++f) {
                const int ar = r0 + f * 16 + am;
                a[f] = *(short8*)&Ash[ar * 64 + (((ks * 4 + aq) ^ (ar & 7)) << 3)];
            }
#pragma unroll
            for (int f = 0; f < 4; ++f) {
                const int br = c0 + f * 16 + am;
                bb[f] = *(short8*)&Bsh[br * 64 + (((ks * 4 + aq) ^ (br & 7)) << 3)];
            }
#pragma unroll
            for (int fi = 0; fi < 4; ++fi)
#pragma unroll
                for (int fj = 0; fj < 4; ++fj)
                    acc[fi][fj] = __builtin_amdgcn_mfma_f32_16x16x32_bf16(
                        a[fi], bb[fj], acc[fi][fj], 0, 0, 0);
        }
    }
    // ---- epilogue: repack C tile in LDS, then coalesced short8 stores ----
    __syncthreads();                  // last MFMA fragment reads done
#pragma unroll
    for (int fj = 0; fj < 4; ++fj) {
        const int col = c0 + fj * 16 + am;
        const float bia = bias[n0 + col];
#pragma unroll
        for (int fi = 0; fi < 4; ++fi)
#pragma unroll
            for (int r = 0; r < 4; ++r)
                Sh[(r0 + fi * 16 + aq * 4 + r) * 128 + col] =
                    f2bf(acc[fi][fj][r] + bia);
    }
    __syncthreads();
#pragma unroll
    for (int s = 0; s < 8; ++s) {
        const int chunk = tid + s * 256;            // 2048 x 16B
        const int row = chunk >> 4, qo = (chunk & 15) * 8;
        *(short8*)(C + (size_t)(m0 + row) * ldc + n0 + qo) =
            *(short8*)&Sh[row * 128 + qo];
    }
}

// ---------------------------------------------------------------------------
// Persistent GRU scan over one time chunk. Grid (32 col-blocks, 16 row-groups)
// = 512 blocks = exactly 2/CU. Whh slice LDS-resident for all TC steps.
// Flag protocol: after computing h_t, each wave shuffle-packs its own 4 rows
// and stores 16 u64 (relaxed agent atomics, write-through to MALL).
// __syncthreads drains every wave's vmcnt, then tid0 stores
// flags[rowgroup*32 + colblock] = step#. At step t+1 wave w polls only its 8
// producer flags (k-range w*128..w*128+127 -> colblocks 8w..8w+7) before the
// MALL-fresh aload16s. A block's 4 waves collectively cover all 32 flags, so
// no block can overwrite parity t-1 before all peers finished step t.
__global__ __launch_bounds__(256, 2) void scan_gru_kernel(
    const u16* __restrict__ gi,      // [TC][256][1536] chunk (bf16)
    const u16* __restrict__ Whh,     // [1536][512] bf16
    const float* __restrict__ bhh,   // [1536] f32
    const int* __restrict__ lengths, // [256]
    const float* __restrict__ h0l,   // [256][512] f32 (layer slice)
    const u16* __restrict__ h0bfl,   // [256][512] bf16 (layer slice)
    u16* __restrict__ o,             // [TC][256][512] chunk (bf16)
    u16* __restrict__ hbf,           // [2][256][512] bf16 state (parity by t)
    float* __restrict__ hlast,       // [256][512] f32 carry (layer slice)
    unsigned* __restrict__ ctr,      // flags: [16 rowgroups][32 colblocks]
    int t0, int TC, unsigned base) {
    __shared__ __attribute__((aligned(16))) u16 Wl[48 * 520];
    __shared__ __attribute__((aligned(16))) float P[4 * 3 * 256];
    __shared__ __attribute__((aligned(16))) float bhhf[48];
    const int tid = threadIdx.x, lane = tid & 63, w = tid >> 6;
    const int n0 = blockIdx.x * 16, b0 = blockIdx.y * 16;
    // one-time: stage Whh slice into LDS (rows: 3 gates x 16 cols, K=512)
#pragma unroll
    for (int it = 0; it < 12; ++it) {
        int f = it * 2048 + tid * 8;
        int j = f >> 9, k = f & 511;
        *(short8*)&Wl[j * 520 + k] =
            *(const short8*)(Whh + ((size_t)((j >> 4) * 512 + n0 + (j & 15))) * 512 + k);
    }
    if (tid < 48) bhhf[tid] = bhh[(tid >> 4) * 512 + n0 + (tid & 15)];
    const int m = tid >> 4, c = tid & 15;
    const int b = b0 + m, col = n0 + c;
    float h = (t0 == 0) ? h0l[(size_t)b * 512 + col]
                        : hlast[(size_t)b * 512 + col];
    const int len = lengths[b];
    const int am = lane & 15, aq = lane >> 4;
    unsigned* flg = ctr + blockIdx.y * 32;          // this row-group's 32 flags
    const unsigned* myprod = flg + w * 8;           // this wave's producers
    // preload step-0 gi into registers
    size_t gib = (size_t)b * (size_t)G3H + n0 + c;
    float gr = bf2f(gi[gib]), gz = bf2f(gi[gib + 512]), gn = bf2f(gi[gib + 1024]);
    __syncthreads();
    for (int tl = 0; tl < TC; ++tl) {
        const int t = t0 + tl;
        if (tl > 0) {  // wait for this wave's 8 producers (divergent loop holds wave)
            const unsigned tgt = base + (unsigned)tl;
            if (lane < 8) {
                const unsigned* fp = myprod + lane;
                while (__hip_atomic_load(fp, __ATOMIC_RELAXED,
                                         __HIP_MEMORY_SCOPE_AGENT) < tgt)
                    __builtin_amdgcn_s_sleep(1);
            }
            asm volatile("" ::: "memory");   // no load hoisting above the poll
        }
        const u16* Asrc = (t == 0) ? h0bfl : (hbf + (size_t)((t - 1) & 1) * BT);
        bf16x8 a4[4];
#pragma unroll
        for (int kb = 0; kb < 4; ++kb)       // issue all 4 MALL loads back-to-back
            a4[kb] = aload16(Asrc + (size_t)(b0 + am) * 512 + w * 128 + kb * 32 + aq * 8);
        f32x4 ar = {}, az = {}, an = {};
#pragma unroll
        for (int kb = 0; kb < 4; ++kb) {
            const int k = w * 128 + kb * 32 + aq * 8;
            bf16x8 wr = *(short8*)&Wl[(0 + am) * 520 + k];
            bf16x8 wz = *(short8*)&Wl[(16 + am) * 520 + k];
            bf16x8 wn = *(short8*)&Wl[(32 + am) * 520 + k];
            ar = __builtin_amdgcn_mfma_f32_16x16x32_bf16(a4[kb], wr, ar, 0, 0, 0);
            az = __builtin_amdgcn_mfma_f32_16x16x32_bf16(a4[kb], wz, az, 0, 0, 0);
            an = __builtin_amdgcn_mfma_f32_16x16x32_bf16(a4[kb], wn, an, 0, 0, 0);
        }
#pragma unroll
        for (int r = 0; r < 4; ++r) {
            P[(w * 3 + 0) * 256 + (aq * 4 + r) * 16 + am] = ar[r];
            P[(w * 3 + 1) * 256 + (aq * 4 + r) * 16 + am] = az[r];
            P[(w * 3 + 2) * 256 + (aq * 4 + r) * 16 + am] = an[r];
        }
        __syncthreads();                                  // (A)
        float Cr = bhhf[c], Cz = bhhf[16 + c], Cn = bhhf[32 + c];
#pragma unroll
        for (int w2 = 0; w2 < 4; ++w2) {
            Cr += P[(w2 * 3 + 0) * 256 + tid];
            Cz += P[(w2 * 3 + 1) * 256 + tid];
            Cn += P[(w2 * 3 + 2) * 256 + tid];
        }
        float r_ = sigm(gr + Cr);
        float z_ = sigm(gz + Cz);
        float n_ = tanh_f(gn + r_ * Cn);
        float hnew = (1.f - z_) * n_ + z_ * h;
        bool valid = t < len;
        h = valid ? hnew : h;
        o[((size_t)tl * 256 + b) * 512 + col] = f2bf(valid ? hnew : 0.f);
        if (tl < TC - 1) {
            // prefetch next step's gi (independent of the publish)
            const size_t gib2 = ((size_t)(tl + 1) * 256 + b) * (size_t)G3H + n0 + c;
            gr = bf2f(gi[gib2]); gz = bf2f(gi[gib2 + 512]); gn = bf2f(gi[gib2 + 1024]);
            // wave-local shuffle-pack: lanes L..L+3 (same batch row) -> one u64
            unsigned hb = (unsigned)f2bf(h);
            unsigned part = hb | ((unsigned)__shfl_down((int)hb, 1) << 16);
            unsigned hi2 = (unsigned)__shfl_down((int)part, 2);
            if ((lane & 3) == 0) {
                u64 q = (u64)part | ((u64)hi2 << 32);
                const int mrow = w * 4 + (lane >> 4);
                const int cg = lane & 15;      // 0,4,8,12
                __hip_atomic_store(
                    (u64*)(hbf + (size_t)(t & 1) * BT + (size_t)(b0 + mrow) * 512 + n0 + cg),
                    q, __ATOMIC_RELAXED, __HIP_MEMORY_SCOPE_AGENT);
            }
            __syncthreads();   // (B) per-wave vmcnt(0) before s_barrier: h visible
            if (tid == 0)
                __hip_atomic_store(flg + blockIdx.x, base + (unsigned)tl + 1u,
                                   __ATOMIC_RELAXED, __HIP_MEMORY_SCOPE_AGENT);
        } else {
            // chunk's last step: next consumer is the next kernel launch
            // (stream order + end-of-kernel writeback) -> plain stores suffice
            hbf[(size_t)(t & 1) * BT + (size_t)b * 512 + col] = f2bf(h);
            hlast[(size_t)b * 512 + col] = h;
        }
    }
}

// ---------------------------------------------------------------------------
// preds as a 128x128 GEMM (N=128 -> one col-block) with fused epilogue:
// rows r = tl*256 + b over the chunk; out[b][t][c] = mask * (acc + b_cov[c]
// + x[t,b,0]*wlast[c]); channel 128 zeroed. Same staging as gemm_bias.
__global__ __launch_bounds__(256) void preds_kernel(
    const u16* __restrict__ o1c, const u16* __restrict__ WcovBf,
    const float* __restrict__ wlastf, const float* __restrict__ bcov,
    const float* __restrict__ x, const int* __restrict__ lengths,
    float* __restrict__ out, int t0) {
    __shared__ __attribute__((aligned(16))) u16 Ash[128 * 64];
    __shared__ __attribute__((aligned(16))) u16 Bsh[128 * 64];
    const int tid = threadIdx.x, lane = tid & 63, w = tid >> 6;
    const int m0 = blockIdx.x * 128;
    const int r0 = (w & 1) * 64, c0 = (w >> 1) * 64;
    const int am = lane & 15, aq = lane >> 4;
    const int l8 = lane >> 3, lc = lane & 7;
    const int swz = (lc ^ l8) << 3;
    f32x4 acc[4][4] = {};
    for (int kt = 0; kt < 512; kt += 64) {
        __syncthreads();
#pragma unroll
        for (int s = 0; s < 4; ++s) {
            const int i = w * 4 + s;
            const int row = i * 8 + l8;
            GLD16(o1c + (size_t)(m0 + row) * 512 + kt + swz, &Ash[i * 512]);
            GLD16(WcovBf + (size_t)row * 512 + kt + swz, &Bsh[i * 512]);
        }
        __syncthreads();
#pragma unroll
        for (int ks = 0; ks < 2; ++ks) {
            bf16x8 a[4], bb[4];
#pragma unroll
            for (int f = 0; f < 4; ++f) {
                const int ar2 = r0 + f * 16 + am;
                a[f] = *(short8*)&Ash[ar2 * 64 + (((ks * 4 + aq) ^ (ar2 & 7)) << 3)];
            }
#pragma unroll
            for (int f = 0; f < 4; ++f) {
                const int br = c0 + f * 16 + am;
                bb[f] = *(short8*)&Bsh[br * 64 + (((ks * 4 + aq) ^ (br & 7)) << 3)];
            }
#pragma unroll
            for (int fi = 0; fi < 4; ++fi)
#pragma unroll
                for (int fj = 0; fj < 4; ++fj)
                    acc[fi][fj] = __builtin_amdgcn_mfma_f32_16x16x32_bf16(
                        a[fi], bb[fj], acc[fi][fj], 0, 0, 0);
        }
    }
    const int tl = m0 >> 8;     // one tl per block (128 rows = half of a tl)
    const int t = t0 + tl;
    if (t < 511) {
#pragma unroll
        for (int fj = 0; fj < 4; ++fj) {
            const int cc = c0 + fj * 16 + am;
            const float bc = bcov[cc], wl = wlastf[cc];
#pragma unroll
            for (int fi = 0; fi < 4; ++fi) {
#pragma unroll
                for (int r = 0; r < 4; ++r) {
                    const int row = m0 + r0 + fi * 16 + aq * 4 + r;
                    const int b = row & 255;
                    const bool valid = t < lengths[b] - 1;
                    const float tim = x[(size_t)t * (256 * 129) + b * 129];
                    out[(size_t)b * (511 * 129) + (size_t)t * 129 + cc] =
                        valid ? acc[fi][fj][r] + bc + tim * wl : 0.f;
                }
            }
        }
        if (tid < 128)  // channel 128 is always zero
            out[(size_t)((m0 & 255) + tid) * (511 * 129) + (size_t)t * 129 + 128] = 0.f;
    }
}

// ---------------------------------------------------------------------------
// dist[i][p] = exp(-(last_flat[i] @ W_par[p] + b_par[p])), f32 out.
__global__ void dist_kernel(const float* __restrict__ hl0,
                            const float* __restrict__ hl1,
                            const float* __restrict__ Wpar,
                            const float* __restrict__ bpar, float* __restrict__ out) {
    const int w = threadIdx.x >> 6, lane = threadIdx.x & 63;
    const float bp0 = bpar[0], bp1 = bpar[1];
    for (int rr = 0; rr < 8; ++rr) {
        const int i = (blockIdx.x * 4 + w) * 8 + rr;
        const int l = i >> 7, bb = (2 * i) & 255;
        const float* base = (l ? hl1 : hl0) + (size_t)bb * 512;
        float a0 = 0.f, a1 = 0.f;
#pragma unroll
        for (int cc = 0; cc < 16; ++cc) {
            const int k = cc * 64 + lane;
            const float v = base[k];
            a0 += v * Wpar[k];
            a1 += v * Wpar[1024 + k];
        }
#pragma unroll
        for (int off = 32; off; off >>= 1) {
            a0 += __shfl_down(a0, off);
            a1 += __shfl_down(a1, off);
        }
        if (lane == 0) {
            out[PRED_ELEMS + i * 2 + 0] = __expf(-(a0 + bp0));
            out[PRED_ELEMS + i * 2 + 1] = __expf(-(a1 + bp1));
        }
    }
}

// ---------------------------------------------------------------------------
extern "C" void kernel_launch(void* const* d_in, const int* in_sizes, int n_in,
                              void* d_out, int out_size, void* d_ws, size_t ws_size,
                              hipStream_t stream) {
    const float* x    = (const float*)d_in[0];
    const int* lens   = (const int*)d_in[1];
    const float* h0   = (const float*)d_in[2];
    const float* Wih0 = (const float*)d_in[3];
    const float* Whh0 = (const float*)d_in[4];
    const float* bih0 = (const float*)d_in[5];
    const float* bhh0 = (const float*)d_in[6];
    const float* Wih1 = (const float*)d_in[7];
    const float* Whh1 = (const float*)d_in[8];
    const float* bih1 = (const float*)d_in[9];
    const float* bhh1 = (const float*)d_in[10];
    const float* Wcov = (const float*)d_in[11];
    const float* bcov = (const float*)d_in[12];
    const float* Wpar = (const float*)d_in[13];
    const float* bpar = (const float*)d_in[14];
    float* out = (float*)d_out;
    char* wsb = (char*)d_ws;

    size_t off = 0;
    auto take = [&](size_t bytes) -> size_t {
        size_t r = off; off += (bytes + 255) & ~(size_t)255; return r;
    };
    const size_t oCtr   = take(8192);                   // 2 layers x 16x32 flags
    const size_t oHl0   = take((size_t)BT * 4);         // layer0 f32 carry
    const size_t oHl1   = take((size_t)BT * 4);         // layer1 f32 carry
    const size_t oHbf0  = take((size_t)2 * BT * 2);     // layer0 bf16 parity
    const size_t oHbf1  = take((size_t)2 * BT * 2);     // layer1 bf16 parity
    const size_t oH0bf  = take((size_t)2 * BT * 2);     // bf16(h0) both layers
    const size_t oWih0b = take((size_t)G3H * XPK * 2);
    const size_t oWih1b = take((size_t)G3H * 512 * 2);
    const size_t oWhh0b = take((size_t)G3H * 512 * 2);
    const size_t oWhh1b = take((size_t)G3H * 512 * 2);
    const size_t oWcovb = take((size_t)128 * 512 * 2);
    const size_t oWlast = take(512);
    const size_t fixed = off;

    const size_t per = (size_t)256 * XPK * 2 + (size_t)256 * G3H * 2 +
                       2 * (size_t)256 * 512 * 2 + 2048;
    const size_t remain = ws_size > fixed ? ws_size - fixed : 0;
    int TC = 1;
    const int cands[10] = {512, 256, 128, 64, 32, 16, 8, 4, 2, 1};
    for (int i = 0; i < 10; ++i)
        if ((size_t)cands[i] * per <= remain) { TC = cands[i]; break; }

    const size_t oXbf = take((size_t)TC * 256 * XPK * 2);
    const size_t oGi  = take((size_t)TC * 256 * G3H * 2);
    const size_t oO0  = take((size_t)TC * 256 * 512 * 2);
    const size_t oO1  = take((size_t)TC * 256 * 512 * 2);

    unsigned* ctr = (unsigned*)(wsb + oCtr);
    float* hl0  = (float*)(wsb + oHl0);
    float* hl1  = (float*)(wsb + oHl1);
    u16* hbf0   = (u16*)(wsb + oHbf0);
    u16* hbf1   = (u16*)(wsb + oHbf1);
    u16* h0bf   = (u16*)(wsb + oH0bf);
    u16* wih0b  = (u16*)(wsb + oWih0b);
    u16* wih1b  = (u16*)(wsb + oWih1b);
    u16* whh0b  = (u16*)(wsb + oWhh0b);
    u16* whh1b  = (u16*)(wsb + oWhh1b);
    u16* wcovb  = (u16*)(wsb + oWcovb);
    float* wlastf = (float*)(wsb + oWlast);
    u16* xbfc   = (u16*)(wsb + oXbf);
    u16* gic    = (u16*)(wsb + oGi);
    u16* o0c    = (u16*)(wsb + oO0);
    u16* o1c    = (u16*)(wsb + oO1);

    prep_kernel<<<1024, 256, 0, stream>>>(Wih0, Wih1, Whh0, Whh1, h0, Wcov,
                                          wih0b, wih1b, whh0b, whh1b, h0bf,
                                          wcovb, wlastf, ctr);

    unsigned base = 0;
    for (int t0 = 0; t0 < T_DIM; t0 += TC) {
        int n = TC * 256 * XPK;
        int pg = (n + 255) / 256; if (pg > 2048) pg = 2048;
        cvt_pad_x_kernel<<<pg, 256, 0, stream>>>(
            x + (size_t)t0 * 256 * 129, xbfc, TC * 256);
        gemm_bias_kernel<<<dim3(12, TC * 2), 256, 0, stream>>>(
            xbfc, XPK, wih0b, XPK, bih0, gic, G3H, XPK);
        scan_gru_kernel<<<dim3(32, 16), 256, 0, stream>>>(
            gic, whh0b, bhh0, lens, h0, h0bf, o0c, hbf0, hl0,
            ctr, t0, TC, base);
        gemm_bias_kernel<<<dim3(12, TC * 2), 256, 0, stream>>>(
            o0c, H_DIM, wih1b, H_DIM, bih1, gic, G3H, H_DIM);
        scan_gru_kernel<<<dim3(32, 16), 256, 0, stream>>>(
            gic, whh1b, bhh1, lens, h0 + (size_t)BT, h0bf + (size_t)BT,
            o1c, hbf1, hl1, ctr + 1024, t0, TC, base);
        preds_kernel<<<dim3(TC * 2), 256, 0, stream>>>(
            o1c, wcovb, wlastf, bcov, x, lens, out, t0);
        base += (unsigned)(TC - 1);
    }
    dist_kernel<<<8, 256, 0, stream>>>(hl0, hl1, Wpar, bpar, out);
}

// Round 4
// 4898.604 us; speedup vs baseline: 1.1668x; 1.0949x over previous
//
#include <hip/hip_runtime.h>

// ---------------------------------------------------------------------------
// BasicModel_43387759624704: 2-layer GRU (T=512, B=256, H=512, COV=128),
// ragged masking, covariate head, exp(-dist) head. Inputs/outputs FLOAT32;
// MFMA operands bf16 in workspace, f32 accumulate/state.
//
// ROUND 11: revert the failed R10 XCD-local experiment; back to the proven
// R9 flag protocol (MALL relaxed-atomic exchange). Two safe deltas:
//  * scan: o-store + gi prefetch moved AFTER the flag publish (off the
//    pre-flag vmcnt drain; they complete under the next poll spin).
//  * gemm_bias/preds: 2-phase double-buffered GLD16 staging (stage tile k+1
//    before computing tile k; ONE __syncthreads per K-tile). LDS 64 KB.
// ---------------------------------------------------------------------------

typedef unsigned short u16;
typedef unsigned long long u64;
typedef __attribute__((ext_vector_type(8))) short short8;
typedef short8 bf16x8;
typedef __attribute__((ext_vector_type(4))) float f32x4;

#define T_DIM 512
#define B_DIM 256
#define H_DIM 512
#define G3H   1536
#define BT    131072        // 256*512
#define XPK   192           // padded K for layer-0 input GEMM (129 -> 192)
#define PRED_ELEMS 16875264 // 256*511*129

// async global->LDS, 16B per lane, wave-uniform LDS base (HW: base + lane*16)
#define GLD16(gp, lp) __builtin_amdgcn_global_load_lds( \
    (const __attribute__((address_space(1))) void*)(gp), \
    (__attribute__((address_space(3))) void*)(lp), 16, 0, 0)

__device__ __forceinline__ u16 f2bf(float f) {  // RNE
    union { float f; unsigned i; } v; v.f = f;
    unsigned i = v.i;
    return (u16)((i + 0x7FFFu + ((i >> 16) & 1u)) >> 16);
}
__device__ __forceinline__ float bf2f(u16 u) {
    union { unsigned i; float f; } v; v.i = ((unsigned)u) << 16; return v.f;
}
__device__ __forceinline__ float sigm(float x) { return 1.f / (1.f + __expf(-x)); }
__device__ __forceinline__ float tanh_f(float x) {
    float ax = fabsf(x);
    float e = __expf(-2.f * ax);
    float t = (1.f - e) / (1.f + e);
    return x < 0.f ? -t : t;
}
// coherent 16B load (2x relaxed agent atomics -> MALL coherence point)
__device__ __forceinline__ bf16x8 aload16(const u16* p) {
    union { bf16x8 v; u64 q[2]; } r;
    const u64* qp = (const u64*)p;
    r.q[0] = __hip_atomic_load(qp + 0, __ATOMIC_RELAXED, __HIP_MEMORY_SCOPE_AGENT);
    r.q[1] = __hip_atomic_load(qp + 1, __ATOMIC_RELAXED, __HIP_MEMORY_SCOPE_AGENT);
    return r.v;
}

// ---------------------------------------------------------------------------
// One-dispatch preamble: flag zero + all weight conversions.
__global__ void prep_kernel(const float* __restrict__ Wih0, const float* __restrict__ Wih1,
                            const float* __restrict__ Whh0, const float* __restrict__ Whh1,
                            const float* __restrict__ h0,   const float* __restrict__ Wcov,
                            u16* __restrict__ wih0b, u16* __restrict__ wih1b,
                            u16* __restrict__ whh0b, u16* __restrict__ whh1b,
                            u16* __restrict__ h0bf,  u16* __restrict__ wcovb,
                            float* __restrict__ wlastf, unsigned* __restrict__ ctr) {
    const int gid = blockIdx.x * 256 + threadIdx.x;
    const int gsz = gridDim.x * 256;
    for (int i = gid; i < 2048; i += gsz) ctr[i] = 0u;
    for (int i = gid; i < 128; i += gsz) wlastf[i] = Wcov[i * 513 + 512];
    for (int i = gid; i < 128 * 512; i += gsz) {
        int r = i >> 9, c = i & 511;
        wcovb[i] = f2bf(Wcov[r * 513 + c]);
    }
    for (int i = gid; i < 512 * 512; i += gsz) h0bf[i] = f2bf(h0[i]);
    for (int i = gid; i < 1536 * 192; i += gsz) {
        int r = i / 192, c = i - r * 192;
        wih0b[i] = f2bf(c < 129 ? Wih0[r * 129 + c] : 0.f);
    }
    for (int i = gid; i < 1536 * 512; i += gsz) wih1b[i] = f2bf(Wih1[i]);
    for (int i = gid; i < 1536 * 512; i += gsz) whh0b[i] = f2bf(Whh0[i]);
    for (int i = gid; i < 1536 * 512; i += gsz) whh1b[i] = f2bf(Whh1[i]);
}

// specialization for x: 129 -> 192, compile-time divisor (magic multiply)
__global__ void cvt_pad_x_kernel(const float* __restrict__ src,
                                 u16* __restrict__ dst, int rows) {
    const int n = rows * 192;
    for (int idx = blockIdx.x * blockDim.x + threadIdx.x; idx < n;
         idx += gridDim.x * blockDim.x) {
        const int row = idx / 192, col = idx - row * 192;
        float v = (col < 129) ? src[(size_t)row * 129 + col] : 0.f;
        dst[idx] = f2bf(v);
    }
}

// ---------------------------------------------------------------------------
// C[m][n] = sum_k A[m][k]*B[n][k] + bias[n]; A,B bf16 K-major; bias f32; C bf16
// 2-phase double-buffered GLD16 staging: stage tile k+1 before computing
// tile k; one __syncthreads per K-tile (drains both the new stage's vmcnt and
// the current tile's ds_reads). Source-side XOR chunk swizzle as before.
__global__ __launch_bounds__(256) void gemm_bias_kernel(
    const u16* __restrict__ A, int lda, const u16* __restrict__ B, int ldb,
    const float* __restrict__ bias, u16* __restrict__ C, int ldc, int K) {
    __shared__ __attribute__((aligned(16))) u16 Sh[2][16384];  // [buf][A|B]
    const int tid = threadIdx.x, lane = tid & 63, w = tid >> 6;
    const int m0 = blockIdx.y * 128, n0 = blockIdx.x * 128;
    const int r0 = (w & 1) * 64, c0 = (w >> 1) * 64;
    const int am = lane & 15, aq = lane >> 4;
    const int l8 = lane >> 3, lc = lane & 7;
    const int swz = (lc ^ l8) << 3;   // source-side swizzled k-chunk (elems)
    const int NT = K >> 6;
    f32x4 acc[4][4] = {};
    // prologue: stage tile 0 -> buf 0
#pragma unroll
    for (int s = 0; s < 4; ++s) {
        const int i = w * 4 + s, row = i * 8 + l8;
        GLD16(A + (size_t)(m0 + row) * lda + swz, &Sh[0][i * 512]);
        GLD16(B + (size_t)(n0 + row) * ldb + swz, &Sh[0][8192 + i * 512]);
    }
    __syncthreads();
    int cur = 0;
    for (int kt = 0; kt < NT; ++kt) {
        if (kt + 1 < NT) {           // stage next tile into the other buffer
            const int kb = (kt + 1) << 6;
#pragma unroll
            for (int s = 0; s < 4; ++s) {
                const int i = w * 4 + s, row = i * 8 + l8;
                GLD16(A + (size_t)(m0 + row) * lda + kb + swz,
                      &Sh[cur ^ 1][i * 512]);
                GLD16(B + (size_t)(n0 + row) * ldb + kb + swz,
                      &Sh[cur ^ 1][8192 + i * 512]);
            }
        }
        const u16* Ash = &Sh[cur][0];
        const u16* Bsh = &Sh[cur][8192];
#pragma unroll
        for (int ks = 0; ks < 2; ++ks) {
            bf16x8 a[4], bb[4];
#pragma unroll
            for (int f = 0; f < 4; ++f) {
                const int ar = r0 + f * 16 + am;
                a[f] = *(short8*)&Ash[ar * 64 + (((ks * 4 + aq) ^ (ar & 7)) << 3)];
            }
#pragma unroll
            for (int f = 0; f < 4; ++f) {
                const int br = c0 + f * 16 + am;
                bb[f] = *(short8*)&Bsh[br * 64 + (((ks * 4 + aq) ^ (br & 7)) << 3)];
            }
#pragma unroll
            for (int fi = 0; fi < 4; ++fi)
#pragma unroll
                for (int fj = 0; fj < 4; ++fj)
                    acc[fi][fj] = __builtin_amdgcn_mfma_f32_16x16x32_bf16(
                        a[fi], bb[fj], acc[fi][fj], 0, 0, 0);
        }
        __syncthreads();             // drains next-tile stage + this tile's reads
        cur ^= 1;
    }
    // ---- epilogue: repack C tile across the whole 64KB LDS, then stream ----
    u16* Ep = &Sh[0][0];             // [128][128] u16 spans both buffers
#pragma unroll
    for (int fj = 0; fj < 4; ++fj) {
        const int col = c0 + fj * 16 + am;
        const float bia = bias[n0 + col];
#pragma unroll
        for (int fi = 0; fi < 4; ++fi)
#pragma unroll
            for (int r = 0; r < 4; ++r)
                Ep[(r0 + fi * 16 + aq * 4 + r) * 128 + col] =
                    f2bf(acc[fi][fj][r] + bia);
    }
    __syncthreads();
#pragma unroll
    for (int s = 0; s < 8; ++s) {
        const int chunk = tid + s * 256;            // 2048 x 16B
        const int row = chunk >> 4, qo = (chunk & 15) * 8;
        *(short8*)(C + (size_t)(m0 + row) * ldc + n0 + qo) =
            *(short8*)&Ep[row * 128 + qo];
    }
}

// ---------------------------------------------------------------------------
// Persistent GRU scan over one time chunk. Grid (32 col-blocks, 16 row-groups)
// = 512 blocks = exactly 2/CU. Whh slice LDS-resident for all TC steps.
// R9 flag protocol: each wave shuffle-packs its 4 h-rows and stores 16 u64
// (relaxed agent atomics, write-through to MALL); __syncthreads drains every
// wave's vmcnt before s_barrier; tid0 stores flags[rg*32+cb] = step#.
// Consumers poll only their 8 producer flags before the MALL-fresh aload16s.
// R11 delta: o-store + gi prefetch issued AFTER the flag (their completion
// rides under the next step's poll spin instead of the pre-flag drain).
__global__ __launch_bounds__(256, 2) void scan_gru_kernel(
    const u16* __restrict__ gi,      // [TC][256][1536] chunk (bf16)
    const u16* __restrict__ Whh,     // [1536][512] bf16
    const float* __restrict__ bhh,   // [1536] f32
    const int* __restrict__ lengths, // [256]
    const float* __restrict__ h0l,   // [256][512] f32 (layer slice)
    const u16* __restrict__ h0bfl,   // [256][512] bf16 (layer slice)
    u16* __restrict__ o,             // [TC][256][512] chunk (bf16)
    u16* __restrict__ hbf,           // [2][256][512] bf16 state (parity by t)
    float* __restrict__ hlast,       // [256][512] f32 carry (layer slice)
    unsigned* __restrict__ ctr,      // flags: [16 rowgroups][32 colblocks]
    int t0, int TC, unsigned base) {
    __shared__ __attribute__((aligned(16))) u16 Wl[48 * 520];
    __shared__ __attribute__((aligned(16))) float P[4 * 3 * 256];
    __shared__ __attribute__((aligned(16))) float bhhf[48];
    const int tid = threadIdx.x, lane = tid & 63, w = tid >> 6;
    const int n0 = blockIdx.x * 16, b0 = blockIdx.y * 16;
    // one-time: stage Whh slice into LDS (rows: 3 gates x 16 cols, K=512)
#pragma unroll
    for (int it = 0; it < 12; ++it) {
        int f = it * 2048 + tid * 8;
        int j = f >> 9, k = f & 511;
        *(short8*)&Wl[j * 520 + k] =
            *(const short8*)(Whh + ((size_t)((j >> 4) * 512 + n0 + (j & 15))) * 512 + k);
    }
    if (tid < 48) bhhf[tid] = bhh[(tid >> 4) * 512 + n0 + (tid & 15)];
    const int m = tid >> 4, c = tid & 15;
    const int b = b0 + m, col = n0 + c;
    float h = (t0 == 0) ? h0l[(size_t)b * 512 + col]
                        : hlast[(size_t)b * 512 + col];
    const int len = lengths[b];
    const int am = lane & 15, aq = lane >> 4;
    unsigned* flg = ctr + blockIdx.y * 32;          // this row-group's 32 flags
    const unsigned* myprod = flg + w * 8;           // this wave's producers
    // preload step-0 gi into registers
    size_t gib = (size_t)b * (size_t)G3H + n0 + c;
    float gr = bf2f(gi[gib]), gz = bf2f(gi[gib + 512]), gn = bf2f(gi[gib + 1024]);
    __syncthreads();
    for (int tl = 0; tl < TC; ++tl) {
        const int t = t0 + tl;
        if (tl > 0) {  // wait for this wave's 8 producers (divergent loop holds wave)
            const unsigned tgt = base + (unsigned)tl;
            if (lane < 8) {
                const unsigned* fp = myprod + lane;
                while (__hip_atomic_load(fp, __ATOMIC_RELAXED,
                                         __HIP_MEMORY_SCOPE_AGENT) < tgt)
                    __builtin_amdgcn_s_sleep(1);
            }
            asm volatile("" ::: "memory");   // no load hoisting above the poll
        }
        const u16* Asrc = (t == 0) ? h0bfl : (hbf + (size_t)((t - 1) & 1) * BT);
        bf16x8 a4[4];
#pragma unroll
        for (int kb = 0; kb < 4; ++kb)       // issue all 4 MALL loads back-to-back
            a4[kb] = aload16(Asrc + (size_t)(b0 + am) * 512 + w * 128 + kb * 32 + aq * 8);
        f32x4 ar = {}, az = {}, an = {};
#pragma unroll
        for (int kb = 0; kb < 4; ++kb) {
            const int k = w * 128 + kb * 32 + aq * 8;
            bf16x8 wr = *(short8*)&Wl[(0 + am) * 520 + k];
            bf16x8 wz = *(short8*)&Wl[(16 + am) * 520 + k];
            bf16x8 wn = *(short8*)&Wl[(32 + am) * 520 + k];
            ar = __builtin_amdgcn_mfma_f32_16x16x32_bf16(a4[kb], wr, ar, 0, 0, 0);
            az = __builtin_amdgcn_mfma_f32_16x16x32_bf16(a4[kb], wz, az, 0, 0, 0);
            an = __builtin_amdgcn_mfma_f32_16x16x32_bf16(a4[kb], wn, an, 0, 0, 0);
        }
#pragma unroll
        for (int r = 0; r < 4; ++r) {
            P[(w * 3 + 0) * 256 + (aq * 4 + r) * 16 + am] = ar[r];
            P[(w * 3 + 1) * 256 + (aq * 4 + r) * 16 + am] = az[r];
            P[(w * 3 + 2) * 256 + (aq * 4 + r) * 16 + am] = an[r];
        }
        __syncthreads();                                  // (A)
        float Cr = bhhf[c], Cz = bhhf[16 + c], Cn = bhhf[32 + c];
#pragma unroll
        for (int w2 = 0; w2 < 4; ++w2) {
            Cr += P[(w2 * 3 + 0) * 256 + tid];
            Cz += P[(w2 * 3 + 1) * 256 + tid];
            Cn += P[(w2 * 3 + 2) * 256 + tid];
        }
        float r_ = sigm(gr + Cr);
        float z_ = sigm(gz + Cz);
        float n_ = tanh_f(gn + r_ * Cn);
        float hnew = (1.f - z_) * n_ + z_ * h;
        bool valid = t < len;
        h = valid ? hnew : h;
        if (tl < TC - 1) {
            // wave-local shuffle-pack: lanes L..L+3 (same batch row) -> one u64
            unsigned hb = (unsigned)f2bf(h);
            unsigned part = hb | ((unsigned)__shfl_down((int)hb, 1) << 16);
            unsigned hi2 = (unsigned)__shfl_down((int)part, 2);
            if ((lane & 3) == 0) {
                u64 q = (u64)part | ((u64)hi2 << 32);
                const int mrow = w * 4 + (lane >> 4);
                const int cg = lane & 15;      // 0,4,8,12
                __hip_atomic_store(
                    (u64*)(hbf + (size_t)(t & 1) * BT + (size_t)(b0 + mrow) * 512 + n0 + cg),
                    q, __ATOMIC_RELAXED, __HIP_MEMORY_SCOPE_AGENT);
            }
            __syncthreads();   // (B) per-wave vmcnt(0) before s_barrier: h visible
            if (tid == 0)
                __hip_atomic_store(flg + blockIdx.x, base + (unsigned)tl + 1u,
                                   __ATOMIC_RELAXED, __HIP_MEMORY_SCOPE_AGENT);
            // off the critical path: completion rides under next step's poll
            o[((size_t)tl * 256 + b) * 512 + col] = f2bf(valid ? hnew : 0.f);
            const size_t gib2 = ((size_t)(tl + 1) * 256 + b) * (size_t)G3H + n0 + c;
            gr = bf2f(gi[gib2]); gz = bf2f(gi[gib2 + 512]); gn = bf2f(gi[gib2 + 1024]);
        } else {
            // chunk's last step: next consumer is the next kernel launch
            // (stream order + end-of-kernel writeback) -> plain stores suffice
            o[((size_t)tl * 256 + b) * 512 + col] = f2bf(valid ? hnew : 0.f);
            hbf[(size_t)(t & 1) * BT + (size_t)b * 512 + col] = f2bf(h);
            hlast[(size_t)b * 512 + col] = h;
        }
    }
}

// ---------------------------------------------------------------------------
// preds as a 128x128 GEMM (N=128 -> one col-block) with fused epilogue:
// out[b][t][c] = mask * (acc + b_cov[c] + x[t,b,0]*wlast[c]); channel 128
// zeroed. Same 2-phase double-buffered staging as gemm_bias.
__global__ __launch_bounds__(256) void preds_kernel(
    const u16* __restrict__ o1c, const u16* __restrict__ WcovBf,
    const float* __restrict__ wlastf, const float* __restrict__ bcov,
    const float* __restrict__ x, const int* __restrict__ lengths,
    float* __restrict__ out, int t0) {
    __shared__ __attribute__((aligned(16))) u16 Sh[2][16384];
    const int tid = threadIdx.x, lane = tid & 63, w = tid >> 6;
    const int m0 = blockIdx.x * 128;
    const int r0 = (w & 1) * 64, c0 = (w >> 1) * 64;
    const int am = lane & 15, aq = lane >> 4;
    const int l8 = lane >> 3, lc = lane & 7;
    const int swz = (lc ^ l8) << 3;
    f32x4 acc[4][4] = {};
#pragma unroll
    for (int s = 0; s < 4; ++s) {
        const int i = w * 4 + s, row = i * 8 + l8;
        GLD16(o1c + (size_t)(m0 + row) * 512 + swz, &Sh[0][i * 512]);
        GLD16(WcovBf + (size_t)row * 512 + swz, &Sh[0][8192 + i * 512]);
    }
    __syncthreads();
    int cur = 0;
    for (int kt = 0; kt < 8; ++kt) {
        if (kt + 1 < 8) {
            const int kb = (kt + 1) << 6;
#pragma unroll
            for (int s = 0; s < 4; ++s) {
                const int i = w * 4 + s, row = i * 8 + l8;
                GLD16(o1c + (size_t)(m0 + row) * 512 + kb + swz,
                      &Sh[cur ^ 1][i * 512]);
                GLD16(WcovBf + (size_t)row * 512 + kb + swz,
                      &Sh[cur ^ 1][8192 + i * 512]);
            }
        }
        const u16* Ash = &Sh[cur][0];
        const u16* Bsh = &Sh[cur][8192];
#pragma unroll
        for (int ks = 0; ks < 2; ++ks) {
            bf16x8 a[4], bb[4];
#pragma unroll
            for (int f = 0; f < 4; ++f) {
                const int ar2 = r0 + f * 16 + am;
                a[f] = *(short8*)&Ash[ar2 * 64 + (((ks * 4 + aq) ^ (ar2 & 7)) << 3)];
            }
#pragma unroll
            for (int f = 0; f < 4; ++f) {
                const int br = c0 + f * 16 + am;
                bb[f] = *(short8*)&Bsh[br * 64 + (((ks * 4 + aq) ^ (br & 7)) << 3)];
            }
#pragma unroll
            for (int fi = 0; fi < 4; ++fi)
#pragma unroll
                for (int fj = 0; fj < 4; ++fj)
                    acc[fi][fj] = __builtin_amdgcn_mfma_f32_16x16x32_bf16(
                        a[fi], bb[fj], acc[fi][fj], 0, 0, 0);
        }
        __syncthreads();
        cur ^= 1;
    }
    const int tl = m0 >> 8;     // one tl per block (128 rows = half of a tl)
    const int t = t0 + tl;
    if (t < 511) {
#pragma unroll
        for (int fj = 0; fj < 4; ++fj) {
            const int cc = c0 + fj * 16 + am;
            const float bc = bcov[cc], wl = wlastf[cc];
#pragma unroll
            for (int fi = 0; fi < 4; ++fi) {
#pragma unroll
                for (int r = 0; r < 4; ++r) {
                    const int row = m0 + r0 + fi * 16 + aq * 4 + r;
                    const int b = row & 255;
                    const bool valid = t < lengths[b] - 1;
                    const float tim = x[(size_t)t * (256 * 129) + b * 129];
                    out[(size_t)b * (511 * 129) + (size_t)t * 129 + cc] =
                        valid ? acc[fi][fj][r] + bc + tim * wl : 0.f;
                }
            }
        }
        if (tid < 128)  // channel 128 is always zero
            out[(size_t)((m0 & 255) + tid) * (511 * 129) + (size_t)t * 129 + 128] = 0.f;
    }
}

// ---------------------------------------------------------------------------
// dist[i][p] = exp(-(last_flat[i] @ W_par[p] + b_par[p])), f32 out.
__global__ void dist_kernel(const float* __restrict__ hl0,
                            const float* __restrict__ hl1,
                            const float* __restrict__ Wpar,
                            const float* __restrict__ bpar, float* __restrict__ out) {
    const int w = threadIdx.x >> 6, lane = threadIdx.x & 63;
    const float bp0 = bpar[0], bp1 = bpar[1];
    for (int rr = 0; rr < 8; ++rr) {
        const int i = (blockIdx.x * 4 + w) * 8 + rr;
        const int l = i >> 7, bb = (2 * i) & 255;
        const float* base = (l ? hl1 : hl0) + (size_t)bb * 512;
        float a0 = 0.f, a1 = 0.f;
#pragma unroll
        for (int cc = 0; cc < 16; ++cc) {
            const int k = cc * 64 + lane;
            const float v = base[k];
            a0 += v * Wpar[k];
            a1 += v * Wpar[1024 + k];
        }
#pragma unroll
        for (int off = 32; off; off >>= 1) {
            a0 += __shfl_down(a0, off);
            a1 += __shfl_down(a1, off);
        }
        if (lane == 0) {
            out[PRED_ELEMS + i * 2 + 0] = __expf(-(a0 + bp0));
            out[PRED_ELEMS + i * 2 + 1] = __expf(-(a1 + bp1));
        }
    }
}

// ---------------------------------------------------------------------------
extern "C" void kernel_launch(void* const* d_in, const int* in_sizes, int n_in,
                              void* d_out, int out_size, void* d_ws, size_t ws_size,
                              hipStream_t stream) {
    const float* x    = (const float*)d_in[0];
    const int* lens   = (const int*)d_in[1];
    const float* h0   = (const float*)d_in[2];
    const float* Wih0 = (const float*)d_in[3];
    const float* Whh0 = (const float*)d_in[4];
    const float* bih0 = (const float*)d_in[5];
    const float* bhh0 = (const float*)d_in[6];
    const float* Wih1 = (const float*)d_in[7];
    const float* Whh1 = (const float*)d_in[8];
    const float* bih1 = (const float*)d_in[9];
    const float* bhh1 = (const float*)d_in[10];
    const float* Wcov = (const float*)d_in[11];
    const float* bcov = (const float*)d_in[12];
    const float* Wpar = (const float*)d_in[13];
    const float* bpar = (const float*)d_in[14];
    float* out = (float*)d_out;
    char* wsb = (char*)d_ws;

    size_t off = 0;
    auto take = [&](size_t bytes) -> size_t {
        size_t r = off; off += (bytes + 255) & ~(size_t)255; return r;
    };
    const size_t oCtr   = take(8192);                   // 2 layers x 16x32 flags
    const size_t oHl0   = take((size_t)BT * 4);         // layer0 f32 carry
    const size_t oHl1   = take((size_t)BT * 4);         // layer1 f32 carry
    const size_t oHbf0  = take((size_t)2 * BT * 2);     // layer0 bf16 parity
    const size_t oHbf1  = take((size_t)2 * BT * 2);     // layer1 bf16 parity
    const size_t oH0bf  = take((size_t)2 * BT * 2);     // bf16(h0) both layers
    const size_t oWih0b = take((size_t)G3H * XPK * 2);
    const size_t oWih1b = take((size_t)G3H * 512 * 2);
    const size_t oWhh0b = take((size_t)G3H * 512 * 2);
    const size_t oWhh1b = take((size_t)G3H * 512 * 2);
    const size_t oWcovb = take((size_t)128 * 512 * 2);
    const size_t oWlast = take(512);
    const size_t fixed = off;

    const size_t per = (size_t)256 * XPK * 2 + (size_t)256 * G3H * 2 +
                       2 * (size_t)256 * 512 * 2 + 2048;
    const size_t remain = ws_size > fixed ? ws_size - fixed : 0;
    int TC = 1;
    const int cands[10] = {512, 256, 128, 64, 32, 16, 8, 4, 2, 1};
    for (int i = 0; i < 10; ++i)
        if ((size_t)cands[i] * per <= remain) { TC = cands[i]; break; }

    const size_t oXbf = take((size_t)TC * 256 * XPK * 2);
    const size_t oGi  = take((size_t)TC * 256 * G3H * 2);
    const size_t oO0  = take((size_t)TC * 256 * 512 * 2);
    const size_t oO1  = take((size_t)TC * 256 * 512 * 2);

    unsigned* ctr = (unsigned*)(wsb + oCtr);
    float* hl0  = (float*)(wsb + oHl0);
    float* hl1  = (float*)(wsb + oHl1);
    u16* hbf0   = (u16*)(wsb + oHbf0);
    u16* hbf1   = (u16*)(wsb + oHbf1);
    u16* h0bf   = (u16*)(wsb + oH0bf);
    u16* wih0b  = (u16*)(wsb + oWih0b);
    u16* wih1b  = (u16*)(wsb + oWih1b);
    u16* whh0b  = (u16*)(wsb + oWhh0b);
    u16* whh1b  = (u16*)(wsb + oWhh1b);
    u16* wcovb  = (u16*)(wsb + oWcovb);
    float* wlastf = (float*)(wsb + oWlast);
    u16* xbfc   = (u16*)(wsb + oXbf);
    u16* gic    = (u16*)(wsb + oGi);
    u16* o0c    = (u16*)(wsb + oO0);
    u16* o1c    = (u16*)(wsb + oO1);

    prep_kernel<<<1024, 256, 0, stream>>>(Wih0, Wih1, Whh0, Whh1, h0, Wcov,
                                          wih0b, wih1b, whh0b, whh1b, h0bf,
                                          wcovb, wlastf, ctr);

    unsigned base = 0;
    for (int t0 = 0; t0 < T_DIM; t0 += TC) {
        int n = TC * 256 * XPK;
        int pg = (n + 255) / 256; if (pg > 2048) pg = 2048;
        cvt_pad_x_kernel<<<pg, 256, 0, stream>>>(
            x + (size_t)t0 * 256 * 129, xbfc, TC * 256);
        gemm_bias_kernel<<<dim3(12, TC * 2), 256, 0, stream>>>(
            xbfc, XPK, wih0b, XPK, bih0, gic, G3H, XPK);
        scan_gru_kernel<<<dim3(32, 16), 256, 0, stream>>>(
            gic, whh0b, bhh0, lens, h0, h0bf, o0c, hbf0, hl0,
            ctr, t0, TC, base);
        gemm_bias_kernel<<<dim3(12, TC * 2), 256, 0, stream>>>(
            o0c, H_DIM, wih1b, H_DIM, bih1, gic, G3H, H_DIM);
        scan_gru_kernel<<<dim3(32, 16), 256, 0, stream>>>(
            gic, whh1b, bhh1, lens, h0 + (size_t)BT, h0bf + (size_t)BT,
            o1c, hbf1, hl1, ctr + 1024, t0, TC, base);
        preds_kernel<<<dim3(TC * 2), 256, 0, stream>>>(
            o1c, wcovb, wlastf, bcov, x, lens, out, t0);
        base += (unsigned)(TC - 1);
    }
    dist_kernel<<<8, 256, 0, stream>>>(hl0, hl1, Wpar, bpar, out);
}

// Round 5
// 4530.705 us; speedup vs baseline: 1.2615x; 1.0812x over previous
//
#include <hip/hip_runtime.h>

// ---------------------------------------------------------------------------
// BasicModel_43387759624704: 2-layer GRU (T=512, B=256, H=512, COV=128),
// ragged masking, covariate head, exp(-dist) head. Inputs/outputs FLOAT32;
// MFMA operands bf16 in workspace, f32 accumulate/state.
//
// ROUND 12: sentinel-dataflow GRU exchange (flag machinery deleted).
//  * o[tl] holds UNMASKED frozen h -> it is both the layer output and the
//    inter-block h broadcast (write-once slots). Downstream masking happens
//    in preds' epilogue, so results are bit-identical.
//  * prep pre-fills o0c/o1c with NaN sentinel 0x7FC0 (unreachable by finite
//    GRU arithmetic). Consumers load o[tl-1] and retry while ANY u16 is
//    sentinel: the poll IS the data load. Producers store h (relaxed agent
//    atomics -> MALL) and proceed: NO vmcnt ack, NO flag, NO barrier (B).
//    Deadlock-free by construction (pure dataflow, nobody waits on readers).
//  * P double-buffered in LDS -> ONE __syncthreads per step; its implicit
//    vmcnt drain is hidden under the next step's exchange-load latency.
//  * Multi-chunk fallback (TC<512) re-sentinels o-chunks between chunks.
//  * gemm_bias/preds/cvt/dist unchanged from R11.
// ---------------------------------------------------------------------------

typedef unsigned short u16;
typedef unsigned long long u64;
typedef __attribute__((ext_vector_type(8))) short short8;
typedef short8 bf16x8;
typedef __attribute__((ext_vector_type(4))) float f32x4;

#define T_DIM 512
#define B_DIM 256
#define H_DIM 512
#define G3H   1536
#define BT    131072        // 256*512
#define XPK   192           // padded K for layer-0 input GEMM (129 -> 192)
#define PRED_ELEMS 16875264 // 256*511*129
#define SENT  0x7FC0u       // bf16 NaN sentinel (finite arithmetic never hits it)

// async global->LDS, 16B per lane, wave-uniform LDS base (HW: base + lane*16)
#define GLD16(gp, lp) __builtin_amdgcn_global_load_lds( \
    (const __attribute__((address_space(1))) void*)(gp), \
    (__attribute__((address_space(3))) void*)(lp), 16, 0, 0)

__device__ __forceinline__ u16 f2bf(float f) {  // RNE
    union { float f; unsigned i; } v; v.f = f;
    unsigned i = v.i;
    return (u16)((i + 0x7FFFu + ((i >> 16) & 1u)) >> 16);
}
__device__ __forceinline__ float bf2f(u16 u) {
    union { unsigned i; float f; } v; v.i = ((unsigned)u) << 16; return v.f;
}
__device__ __forceinline__ float sigm(float x) { return 1.f / (1.f + __expf(-x)); }
__device__ __forceinline__ float tanh_f(float x) {
    float ax = fabsf(x);
    float e = __expf(-2.f * ax);
    float t = (1.f - e) / (1.f + e);
    return x < 0.f ? -t : t;
}
// coherent 16B load (2x relaxed agent atomics -> MALL coherence point)
__device__ __forceinline__ bf16x8 aload16(const u16* p) {
    union { bf16x8 v; u64 q[2]; } r;
    const u64* qp = (const u64*)p;
    r.q[0] = __hip_atomic_load(qp + 0, __ATOMIC_RELAXED, __HIP_MEMORY_SCOPE_AGENT);
    r.q[1] = __hip_atomic_load(qp + 1, __ATOMIC_RELAXED, __HIP_MEMORY_SCOPE_AGENT);
    return r.v;
}
// 1 if any of the 8 bf16 halves equals the sentinel
__device__ __forceinline__ unsigned chk8(bf16x8 v) {
    union { bf16x8 v; unsigned d[4]; } u; u.v = v;
    unsigned b = 0;
#pragma unroll
    for (int i = 0; i < 4; ++i) {
        unsigned d = u.d[i] ^ 0x7FC07FC0u;
        b |= (unsigned)((d & 0xFFFFu) == 0u) | (unsigned)((d >> 16) == 0u);
    }
    return b;
}

// ---------------------------------------------------------------------------
// One-dispatch preamble: weight conversions + o-chunk sentinel fill.
__global__ void prep_kernel(const float* __restrict__ Wih0, const float* __restrict__ Wih1,
                            const float* __restrict__ Whh0, const float* __restrict__ Whh1,
                            const float* __restrict__ h0,   const float* __restrict__ Wcov,
                            u16* __restrict__ wih0b, u16* __restrict__ wih1b,
                            u16* __restrict__ whh0b, u16* __restrict__ whh1b,
                            u16* __restrict__ h0bf,  u16* __restrict__ wcovb,
                            float* __restrict__ wlastf,
                            u16* __restrict__ o0c, u16* __restrict__ o1c, int TC) {
    const int gid = blockIdx.x * 256 + threadIdx.x;
    const int gsz = gridDim.x * 256;
    for (int i = gid; i < 128; i += gsz) wlastf[i] = Wcov[i * 513 + 512];
    for (int i = gid; i < 128 * 512; i += gsz) {
        int r = i >> 9, c = i & 511;
        wcovb[i] = f2bf(Wcov[r * 513 + c]);
    }
    for (int i = gid; i < 512 * 512; i += gsz) h0bf[i] = f2bf(h0[i]);
    for (int i = gid; i < 1536 * 192; i += gsz) {
        int r = i / 192, c = i - r * 192;
        wih0b[i] = f2bf(c < 129 ? Wih0[r * 129 + c] : 0.f);
    }
    for (int i = gid; i < 1536 * 512; i += gsz) wih1b[i] = f2bf(Wih1[i]);
    for (int i = gid; i < 1536 * 512; i += gsz) whh0b[i] = f2bf(Whh0[i]);
    for (int i = gid; i < 1536 * 512; i += gsz) whh1b[i] = f2bf(Whh1[i]);
    // sentinel fill (u64 stores)
    const u64 SQ = 0x7FC07FC07FC07FC0ULL;
    const size_t nq = (size_t)TC * BT / 4;
    u64* p0 = (u64*)o0c;
    u64* p1 = (u64*)o1c;
    for (size_t i = gid; i < nq; i += gsz) p0[i] = SQ;
    for (size_t i = gid; i < nq; i += gsz) p1[i] = SQ;
}

// multi-chunk fallback: re-sentinel an o-chunk between chunks
__global__ void sentinel_kernel(u16* __restrict__ buf, int TC) {
    const u64 SQ = 0x7FC07FC07FC07FC0ULL;
    const size_t nq = (size_t)TC * BT / 4;
    u64* p = (u64*)buf;
    const size_t gid = blockIdx.x * 256 + threadIdx.x;
    const size_t gsz = (size_t)gridDim.x * 256;
    for (size_t i = gid; i < nq; i += gsz) p[i] = SQ;
}

// specialization for x: 129 -> 192, compile-time divisor (magic multiply)
__global__ void cvt_pad_x_kernel(const float* __restrict__ src,
                                 u16* __restrict__ dst, int rows) {
    const int n = rows * 192;
    for (int idx = blockIdx.x * blockDim.x + threadIdx.x; idx < n;
         idx += gridDim.x * blockDim.x) {
        const int row = idx / 192, col = idx - row * 192;
        float v = (col < 129) ? src[(size_t)row * 129 + col] : 0.f;
        dst[idx] = f2bf(v);
    }
}

// ---------------------------------------------------------------------------
// C[m][n] = sum_k A[m][k]*B[n][k] + bias[n]; A,B bf16 K-major; bias f32; C bf16
// 2-phase double-buffered GLD16 staging (R11), source-side XOR chunk swizzle.
__global__ __launch_bounds__(256) void gemm_bias_kernel(
    const u16* __restrict__ A, int lda, const u16* __restrict__ B, int ldb,
    const float* __restrict__ bias, u16* __restrict__ C, int ldc, int K) {
    __shared__ __attribute__((aligned(16))) u16 Sh[2][16384];  // [buf][A|B]
    const int tid = threadIdx.x, lane = tid & 63, w = tid >> 6;
    const int m0 = blockIdx.y * 128, n0 = blockIdx.x * 128;
    const int r0 = (w & 1) * 64, c0 = (w >> 1) * 64;
    const int am = lane & 15, aq = lane >> 4;
    const int l8 = lane >> 3, lc = lane & 7;
    const int swz = (lc ^ l8) << 3;   // source-side swizzled k-chunk (elems)
    const int NT = K >> 6;
    f32x4 acc[4][4] = {};
    // prologue: stage tile 0 -> buf 0
#pragma unroll
    for (int s = 0; s < 4; ++s) {
        const int i = w * 4 + s, row = i * 8 + l8;
        GLD16(A + (size_t)(m0 + row) * lda + swz, &Sh[0][i * 512]);
        GLD16(B + (size_t)(n0 + row) * ldb + swz, &Sh[0][8192 + i * 512]);
    }
    __syncthreads();
    int cur = 0;
    for (int kt = 0; kt < NT; ++kt) {
        if (kt + 1 < NT) {           // stage next tile into the other buffer
            const int kb = (kt + 1) << 6;
#pragma unroll
            for (int s = 0; s < 4; ++s) {
                const int i = w * 4 + s, row = i * 8 + l8;
                GLD16(A + (size_t)(m0 + row) * lda + kb + swz,
                      &Sh[cur ^ 1][i * 512]);
                GLD16(B + (size_t)(n0 + row) * ldb + kb + swz,
                      &Sh[cur ^ 1][8192 + i * 512]);
            }
        }
        const u16* Ash = &Sh[cur][0];
        const u16* Bsh = &Sh[cur][8192];
#pragma unroll
        for (int ks = 0; ks < 2; ++ks) {
            bf16x8 a[4], bb[4];
#pragma unroll
            for (int f = 0; f < 4; ++f) {
                const int ar = r0 + f * 16 + am;
                a[f] = *(short8*)&Ash[ar * 64 + (((ks * 4 + aq) ^ (ar & 7)) << 3)];
            }
#pragma unroll
            for (int f = 0; f < 4; ++f) {
                const int br = c0 + f * 16 + am;
                bb[f] = *(short8*)&Bsh[br * 64 + (((ks * 4 + aq) ^ (br & 7)) << 3)];
            }
#pragma unroll
            for (int fi = 0; fi < 4; ++fi)
#pragma unroll
                for (int fj = 0; fj < 4; ++fj)
                    acc[fi][fj] = __builtin_amdgcn_mfma_f32_16x16x32_bf16(
                        a[fi], bb[fj], acc[fi][fj], 0, 0, 0);
        }
        __syncthreads();             // drains next-tile stage + this tile's reads
        cur ^= 1;
    }
    // ---- epilogue: repack C tile across the whole 64KB LDS, then stream ----
    u16* Ep = &Sh[0][0];             // [128][128] u16 spans both buffers
#pragma unroll
    for (int fj = 0; fj < 4; ++fj) {
        const int col = c0 + fj * 16 + am;
        const float bia = bias[n0 + col];
#pragma unroll
        for (int fi = 0; fi < 4; ++fi)
#pragma unroll
            for (int r = 0; r < 4; ++r)
                Ep[(r0 + fi * 16 + aq * 4 + r) * 128 + col] =
                    f2bf(acc[fi][fj][r] + bia);
    }
    __syncthreads();
#pragma unroll
    for (int s = 0; s < 8; ++s) {
        const int chunk = tid + s * 256;            // 2048 x 16B
        const int row = chunk >> 4, qo = (chunk & 15) * 8;
        *(short8*)(C + (size_t)(m0 + row) * ldc + n0 + qo) =
            *(short8*)&Ep[row * 128 + qo];
    }
}

// ---------------------------------------------------------------------------
// Persistent GRU scan. Grid (32 col-blocks, 16 row-groups) = 512 blocks.
// Sentinel-dataflow protocol: o[tl] = frozen h (write-once). Consumers load
// o[tl-1] and retry while any u16 == SENT. Producers store h via relaxed
// agent atomics (write-through MALL) with no ack/flag/extra barrier.
// P double-buffered -> one __syncthreads per step.
__global__ __launch_bounds__(256, 2) void scan_gru_kernel(
    const u16* __restrict__ gi,      // [TC][256][1536] chunk (bf16)
    const u16* __restrict__ Whh,     // [1536][512] bf16
    const float* __restrict__ bhh,   // [1536] f32
    const int* __restrict__ lengths, // [256]
    const float* __restrict__ h0l,   // [256][512] f32 (layer slice)
    const u16* __restrict__ h0bfl,   // [256][512] bf16 (layer slice)
    u16* __restrict__ o,             // [TC][256][512] chunk: output AND exchange
    u16* __restrict__ hcarry,        // [256][512] bf16 cross-chunk carry
    float* __restrict__ hlast,       // [256][512] f32 carry (layer slice)
    int t0, int TC) {
    __shared__ __attribute__((aligned(16))) u16 Wl[48 * 520];
    __shared__ __attribute__((aligned(16))) float P[2][12 * 256];
    __shared__ __attribute__((aligned(16))) float bhhf[48];
    const int tid = threadIdx.x, lane = tid & 63, w = tid >> 6;
    const int n0 = blockIdx.x * 16, b0 = blockIdx.y * 16;
    // one-time: stage Whh slice into LDS (rows: 3 gates x 16 cols, K=512)
#pragma unroll
    for (int it = 0; it < 12; ++it) {
        int f = it * 2048 + tid * 8;
        int j = f >> 9, k = f & 511;
        *(short8*)&Wl[j * 520 + k] =
            *(const short8*)(Whh + ((size_t)((j >> 4) * 512 + n0 + (j & 15))) * 512 + k);
    }
    if (tid < 48) bhhf[tid] = bhh[(tid >> 4) * 512 + n0 + (tid & 15)];
    const int m = tid >> 4, c = tid & 15;
    const int b = b0 + m, col = n0 + c;
    float h = (t0 == 0) ? h0l[(size_t)b * 512 + col]
                        : hlast[(size_t)b * 512 + col];
    const int len = lengths[b];
    const int am = lane & 15, aq = lane >> 4;
    // preload step-0 gi into registers
    size_t gib = (size_t)b * (size_t)G3H + n0 + c;
    float gr = bf2f(gi[gib]), gz = bf2f(gi[gib + 512]), gn = bf2f(gi[gib + 1024]);
    __syncthreads();
    int pb = 0;
    for (int tl = 0; tl < TC; ++tl) {
        const int t = t0 + tl;
        const u16* Asrc = (tl == 0) ? ((t0 == 0) ? h0bfl : hcarry)
                                    : (o + (size_t)(tl - 1) * BT);
        const u16* arow = Asrc + (size_t)(b0 + am) * 512 + w * 128 + aq * 8;
        bf16x8 av[4];
        if (tl == 0) {   // clean source (earlier dispatch), no sentinel check
            av[0] = aload16(arow);      av[1] = aload16(arow + 32);
            av[2] = aload16(arow + 64); av[3] = aload16(arow + 96);
        } else {
            for (;;) {   // cheap probe on first chunk, then the rest
                av[0] = aload16(arow);
                if (!__any((int)chk8(av[0]))) break;
                __builtin_amdgcn_s_sleep(1);
            }
            for (;;) {
                av[1] = aload16(arow + 32);
                av[2] = aload16(arow + 64);
                av[3] = aload16(arow + 96);
                if (!__any((int)(chk8(av[1]) | chk8(av[2]) | chk8(av[3])))) break;
                __builtin_amdgcn_s_sleep(1);
            }
        }
        f32x4 ar = {}, az = {}, an = {};
#pragma unroll
        for (int kb = 0; kb < 4; ++kb) {
            const int k = w * 128 + kb * 32 + aq * 8;
            bf16x8 wr = *(short8*)&Wl[(0 + am) * 520 + k];
            bf16x8 wz = *(short8*)&Wl[(16 + am) * 520 + k];
            bf16x8 wn = *(short8*)&Wl[(32 + am) * 520 + k];
            ar = __builtin_amdgcn_mfma_f32_16x16x32_bf16(av[kb], wr, ar, 0, 0, 0);
            az = __builtin_amdgcn_mfma_f32_16x16x32_bf16(av[kb], wz, az, 0, 0, 0);
            an = __builtin_amdgcn_mfma_f32_16x16x32_bf16(av[kb], wn, an, 0, 0, 0);
        }
#pragma unroll
        for (int r = 0; r < 4; ++r) {
            P[pb][(w * 3 + 0) * 256 + (aq * 4 + r) * 16 + am] = ar[r];
            P[pb][(w * 3 + 1) * 256 + (aq * 4 + r) * 16 + am] = az[r];
            P[pb][(w * 3 + 2) * 256 + (aq * 4 + r) * 16 + am] = an[r];
        }
        __syncthreads();   // P[pb] visible; implicit vmcnt drain hidden by the
                           // ~700cy exchange-load that preceded it this step
        float Cr = bhhf[c], Cz = bhhf[16 + c], Cn = bhhf[32 + c];
#pragma unroll
        for (int w2 = 0; w2 < 4; ++w2) {
            Cr += P[pb][(w2 * 3 + 0) * 256 + tid];
            Cz += P[pb][(w2 * 3 + 1) * 256 + tid];
            Cn += P[pb][(w2 * 3 + 2) * 256 + tid];
        }
        float r_ = sigm(gr + Cr);
        float z_ = sigm(gz + Cz);
        float n_ = tanh_f(gn + r_ * Cn);
        float hnew = (1.f - z_) * n_ + z_ * h;
        h = (t < len) ? hnew : h;    // freeze past length
        // publish o[tl] = frozen h (output AND exchange; masked downstream)
        unsigned hb = (unsigned)f2bf(h);
        unsigned part = hb | ((unsigned)__shfl_down((int)hb, 1) << 16);
        unsigned hi2 = (unsigned)__shfl_down((int)part, 2);
        if ((lane & 3) == 0) {
            u64 q = (u64)part | ((u64)hi2 << 32);
            const int mrow = w * 4 + (lane >> 4);
            const int cg = lane & 15;      // 0,4,8,12
            __hip_atomic_store(
                (u64*)(o + (size_t)tl * BT + (size_t)(b0 + mrow) * 512 + n0 + cg),
                q, __ATOMIC_RELAXED, __HIP_MEMORY_SCOPE_AGENT);
        }
        if (tl < TC - 1) {
            // next step's gi prefetch: completes under the next exchange load
            const size_t gib2 = ((size_t)(tl + 1) * 256 + b) * (size_t)G3H + n0 + c;
            gr = bf2f(gi[gib2]); gz = bf2f(gi[gib2 + 512]); gn = bf2f(gi[gib2 + 1024]);
        } else {
            // cross-chunk / cross-launch carries (plain stores, stream order)
            hcarry[(size_t)b * 512 + col] = f2bf(h);
            hlast[(size_t)b * 512 + col] = h;
        }
        pb ^= 1;
    }
}

// ---------------------------------------------------------------------------
// preds as a 128x128 GEMM (N=128 -> one col-block) with fused epilogue:
// out[b][t][c] = mask * (acc + b_cov[c] + x[t,b,0]*wlast[c]); channel 128
// zeroed. NOTE: o1c rows past len hold frozen h (not 0); the t < len-1 mask
// here is what the reference applies, so outputs are identical.
__global__ __launch_bounds__(256) void preds_kernel(
    const u16* __restrict__ o1c, const u16* __restrict__ WcovBf,
    const float* __restrict__ wlastf, const float* __restrict__ bcov,
    const float* __restrict__ x, const int* __restrict__ lengths,
    float* __restrict__ out, int t0) {
    __shared__ __attribute__((aligned(16))) u16 Sh[2][16384];
    const int tid = threadIdx.x, lane = tid & 63, w = tid >> 6;
    const int m0 = blockIdx.x * 128;
    const int r0 = (w & 1) * 64, c0 = (w >> 1) * 64;
    const int am = lane & 15, aq = lane >> 4;
    const int l8 = lane >> 3, lc = lane & 7;
    const int swz = (lc ^ l8) << 3;
    f32x4 acc[4][4] = {};
#pragma unroll
    for (int s = 0; s < 4; ++s) {
        const int i = w * 4 + s, row = i * 8 + l8;
        GLD16(o1c + (size_t)(m0 + row) * 512 + swz, &Sh[0][i * 512]);
        GLD16(WcovBf + (size_t)row * 512 + swz, &Sh[0][8192 + i * 512]);
    }
    __syncthreads();
    int cur = 0;
    for (int kt = 0; kt < 8; ++kt) {
        if (kt + 1 < 8) {
            const int kb = (kt + 1) << 6;
#pragma unroll
            for (int s = 0; s < 4; ++s) {
                const int i = w * 4 + s, row = i * 8 + l8;
                GLD16(o1c + (size_t)(m0 + row) * 512 + kb + swz,
                      &Sh[cur ^ 1][i * 512]);
                GLD16(WcovBf + (size_t)row * 512 + kb + swz,
                      &Sh[cur ^ 1][8192 + i * 512]);
            }
        }
        const u16* Ash = &Sh[cur][0];
        const u16* Bsh = &Sh[cur][8192];
#pragma unroll
        for (int ks = 0; ks < 2; ++ks) {
            bf16x8 a[4], bb[4];
#pragma unroll
            for (int f = 0; f < 4; ++f) {
                const int ar2 = r0 + f * 16 + am;
                a[f] = *(short8*)&Ash[ar2 * 64 + (((ks * 4 + aq) ^ (ar2 & 7)) << 3)];
            }
#pragma unroll
            for (int f = 0; f < 4; ++f) {
                const int br = c0 + f * 16 + am;
                bb[f] = *(short8*)&Bsh[br * 64 + (((ks * 4 + aq) ^ (br & 7)) << 3)];
            }
#pragma unroll
            for (int fi = 0; fi < 4; ++fi)
#pragma unroll
                for (int fj = 0; fj < 4; ++fj)
                    acc[fi][fj] = __builtin_amdgcn_mfma_f32_16x16x32_bf16(
                        a[fi], bb[fj], acc[fi][fj], 0, 0, 0);
        }
        __syncthreads();
        cur ^= 1;
    }
    const int tl = m0 >> 8;     // one tl per block (128 rows = half of a tl)
    const int t = t0 + tl;
    if (t < 511) {
#pragma unroll
        for (int fj = 0; fj < 4; ++fj) {
            const int cc = c0 + fj * 16 + am;
            const float bc = bcov[cc], wl = wlastf[cc];
#pragma unroll
            for (int fi = 0; fi < 4; ++fi) {
#pragma unroll
                for (int r = 0; r < 4; ++r) {
                    const int row = m0 + r0 + fi * 16 + aq * 4 + r;
                    const int b = row & 255;
                    const bool valid = t < lengths[b] - 1;
                    const float tim = x[(size_t)t * (256 * 129) + b * 129];
                    out[(size_t)b * (511 * 129) + (size_t)t * 129 + cc] =
                        valid ? acc[fi][fj][r] + bc + tim * wl : 0.f;
                }
            }
        }
        if (tid < 128)  // channel 128 is always zero
            out[(size_t)((m0 & 255) + tid) * (511 * 129) + (size_t)t * 129 + 128] = 0.f;
    }
}

// ---------------------------------------------------------------------------
// dist[i][p] = exp(-(last_flat[i] @ W_par[p] + b_par[p])), f32 out.
__global__ void dist_kernel(const float* __restrict__ hl0,
                            const float* __restrict__ hl1,
                            const float* __restrict__ Wpar,
                            const float* __restrict__ bpar, float* __restrict__ out) {
    const int w = threadIdx.x >> 6, lane = threadIdx.x & 63;
    const float bp0 = bpar[0], bp1 = bpar[1];
    for (int rr = 0; rr < 8; ++rr) {
        const int i = (blockIdx.x * 4 + w) * 8 + rr;
        const int l = i >> 7, bb = (2 * i) & 255;
        const float* base = (l ? hl1 : hl0) + (size_t)bb * 512;
        float a0 = 0.f, a1 = 0.f;
#pragma unroll
        for (int cc = 0; cc < 16; ++cc) {
            const int k = cc * 64 + lane;
            const float v = base[k];
            a0 += v * Wpar[k];
            a1 += v * Wpar[1024 + k];
        }
#pragma unroll
        for (int off = 32; off; off >>= 1) {
            a0 += __shfl_down(a0, off);
            a1 += __shfl_down(a1, off);
        }
        if (lane == 0) {
            out[PRED_ELEMS + i * 2 + 0] = __expf(-(a0 + bp0));
            out[PRED_ELEMS + i * 2 + 1] = __expf(-(a1 + bp1));
        }
    }
}

// ---------------------------------------------------------------------------
extern "C" void kernel_launch(void* const* d_in, const int* in_sizes, int n_in,
                              void* d_out, int out_size, void* d_ws, size_t ws_size,
                              hipStream_t stream) {
    const float* x    = (const float*)d_in[0];
    const int* lens   = (const int*)d_in[1];
    const float* h0   = (const float*)d_in[2];
    const float* Wih0 = (const float*)d_in[3];
    const float* Whh0 = (const float*)d_in[4];
    const float* bih0 = (const float*)d_in[5];
    const float* bhh0 = (const float*)d_in[6];
    const float* Wih1 = (const float*)d_in[7];
    const float* Whh1 = (const float*)d_in[8];
    const float* bih1 = (const float*)d_in[9];
    const float* bhh1 = (const float*)d_in[10];
    const float* Wcov = (const float*)d_in[11];
    const float* bcov = (const float*)d_in[12];
    const float* Wpar = (const float*)d_in[13];
    const float* bpar = (const float*)d_in[14];
    float* out = (float*)d_out;
    char* wsb = (char*)d_ws;

    size_t off = 0;
    auto take = [&](size_t bytes) -> size_t {
        size_t r = off; off += (bytes + 255) & ~(size_t)255; return r;
    };
    const size_t oHl0   = take((size_t)BT * 4);         // layer0 f32 carry
    const size_t oHl1   = take((size_t)BT * 4);         // layer1 f32 carry
    const size_t oHc0   = take((size_t)BT * 2);         // layer0 bf16 chunk carry
    const size_t oHc1   = take((size_t)BT * 2);         // layer1 bf16 chunk carry
    const size_t oH0bf  = take((size_t)2 * BT * 2);     // bf16(h0) both layers
    const size_t oWih0b = take((size_t)G3H * XPK * 2);
    const size_t oWih1b = take((size_t)G3H * 512 * 2);
    const size_t oWhh0b = take((size_t)G3H * 512 * 2);
    const size_t oWhh1b = take((size_t)G3H * 512 * 2);
    const size_t oWcovb = take((size_t)128 * 512 * 2);
    const size_t oWlast = take(512);
    const size_t fixed = off;

    const size_t per = (size_t)256 * XPK * 2 + (size_t)256 * G3H * 2 +
                       2 * (size_t)256 * 512 * 2 + 2048;
    const size_t remain = ws_size > fixed ? ws_size - fixed : 0;
    int TC = 1;
    const int cands[10] = {512, 256, 128, 64, 32, 16, 8, 4, 2, 1};
    for (int i = 0; i < 10; ++i)
        if ((size_t)cands[i] * per <= remain) { TC = cands[i]; break; }

    const size_t oXbf = take((size_t)TC * 256 * XPK * 2);
    const size_t oGi  = take((size_t)TC * 256 * G3H * 2);
    const size_t oO0  = take((size_t)TC * 256 * 512 * 2);
    const size_t oO1  = take((size_t)TC * 256 * 512 * 2);

    float* hl0  = (float*)(wsb + oHl0);
    float* hl1  = (float*)(wsb + oHl1);
    u16* hcar0  = (u16*)(wsb + oHc0);
    u16* hcar1  = (u16*)(wsb + oHc1);
    u16* h0bf   = (u16*)(wsb + oH0bf);
    u16* wih0b  = (u16*)(wsb + oWih0b);
    u16* wih1b  = (u16*)(wsb + oWih1b);
    u16* whh0b  = (u16*)(wsb + oWhh0b);
    u16* whh1b  = (u16*)(wsb + oWhh1b);
    u16* wcovb  = (u16*)(wsb + oWcovb);
    float* wlastf = (float*)(wsb + oWlast);
    u16* xbfc   = (u16*)(wsb + oXbf);
    u16* gic    = (u16*)(wsb + oGi);
    u16* o0c    = (u16*)(wsb + oO0);
    u16* o1c    = (u16*)(wsb + oO1);

    prep_kernel<<<1024, 256, 0, stream>>>(Wih0, Wih1, Whh0, Whh1, h0, Wcov,
                                          wih0b, wih1b, whh0b, whh1b, h0bf,
                                          wcovb, wlastf, o0c, o1c, TC);

    for (int t0 = 0; t0 < T_DIM; t0 += TC) {
        int n = TC * 256 * XPK;
        int pg = (n + 255) / 256; if (pg > 2048) pg = 2048;
        cvt_pad_x_kernel<<<pg, 256, 0, stream>>>(
            x + (size_t)t0 * 256 * 129, xbfc, TC * 256);
        gemm_bias_kernel<<<dim3(12, TC * 2), 256, 0, stream>>>(
            xbfc, XPK, wih0b, XPK, bih0, gic, G3H, XPK);
        if (t0 > 0)   // multi-chunk fallback: re-arm sentinels
            sentinel_kernel<<<2048, 256, 0, stream>>>(o0c, TC);
        scan_gru_kernel<<<dim3(32, 16), 256, 0, stream>>>(
            gic, whh0b, bhh0, lens, h0, h0bf, o0c, hcar0, hl0, t0, TC);
        gemm_bias_kernel<<<dim3(12, TC * 2), 256, 0, stream>>>(
            o0c, H_DIM, wih1b, H_DIM, bih1, gic, G3H, H_DIM);
        if (t0 > 0)
            sentinel_kernel<<<2048, 256, 0, stream>>>(o1c, TC);
        scan_gru_kernel<<<dim3(32, 16), 256, 0, stream>>>(
            gic, whh1b, bhh1, lens, h0 + (size_t)BT, h0bf + (size_t)BT,
            o1c, hcar1, hl1, t0, TC);
        preds_kernel<<<dim3(TC * 2), 256, 0, stream>>>(
            o1c, wcovb, wlastf, bcov, x, lens, out, t0);
    }
    dist_kernel<<<8, 256, 0, stream>>>(hl0, hl1, Wpar, bpar, out);
}

// Round 6
// 4046.616 us; speedup vs baseline: 1.4124x; 1.1196x over previous
//
#include <hip/hip_runtime.h>

// ---------------------------------------------------------------------------
// BasicModel_43387759624704: 2-layer GRU (T=512, B=256, H=512, COV=128),
// ragged masking, covariate head, exp(-dist) head. Inputs/outputs FLOAT32;
// MFMA operands bf16 in workspace, f32 accumulate/state.
//
// ROUND 13: FUSED input GEMM + scan (gemm0/gemm1/gic deleted).
//  * scan_fused<AK>: per step, out[b][c] = x-part (xin[t] @ Wih^T, Wih frags
//    REGISTER-resident, computed BEFORE the h-poll -> off critical path)
//    + h-part (h_{t-1} @ Whh^T, Whh slice LDS-resident). Gate n keeps x/h
//    parts separate (n = tanh(i_n + r*h_n)) -> 4-row/wave P reduce, single
//    P buffer (16KB), two barriers/step; barrier B BEFORE the publish so the
//    h-store ack stays off the critical path (R12 property preserved).
//  * Sentinel-dataflow exchange unchanged from R12 (o[tl] = frozen h slots,
//    NaN sentinel, poll = data load).
//  * Layer1's x-input is o0c (complete, stream order). Layer0's is xbfc
//    (pad 129->256). preds/dist unchanged; prep loses nothing but gic.
// ---------------------------------------------------------------------------

typedef unsigned short u16;
typedef unsigned long long u64;
typedef __attribute__((ext_vector_type(8))) short short8;
typedef short8 bf16x8;
typedef __attribute__((ext_vector_type(4))) float f32x4;

#define T_DIM 512
#define B_DIM 256
#define H_DIM 512
#define G3H   1536
#define BT    131072        // 256*512
#define XPK   256           // padded K for layer-0 x (129 -> 256)
#define PRED_ELEMS 16875264 // 256*511*129

// async global->LDS, 16B per lane, wave-uniform LDS base (HW: base + lane*16)
#define GLD16(gp, lp) __builtin_amdgcn_global_load_lds( \
    (const __attribute__((address_space(1))) void*)(gp), \
    (__attribute__((address_space(3))) void*)(lp), 16, 0, 0)

__device__ __forceinline__ u16 f2bf(float f) {  // RNE
    union { float f; unsigned i; } v; v.f = f;
    unsigned i = v.i;
    return (u16)((i + 0x7FFFu + ((i >> 16) & 1u)) >> 16);
}
__device__ __forceinline__ float bf2f(u16 u) {
    union { unsigned i; float f; } v; v.i = ((unsigned)u) << 16; return v.f;
}
__device__ __forceinline__ float sigm(float x) { return 1.f / (1.f + __expf(-x)); }
__device__ __forceinline__ float tanh_f(float x) {
    float ax = fabsf(x);
    float e = __expf(-2.f * ax);
    float t = (1.f - e) / (1.f + e);
    return x < 0.f ? -t : t;
}
// coherent 16B load (2x relaxed agent atomics -> MALL coherence point)
__device__ __forceinline__ bf16x8 aload16(const u16* p) {
    union { bf16x8 v; u64 q[2]; } r;
    const u64* qp = (const u64*)p;
    r.q[0] = __hip_atomic_load(qp + 0, __ATOMIC_RELAXED, __HIP_MEMORY_SCOPE_AGENT);
    r.q[1] = __hip_atomic_load(qp + 1, __ATOMIC_RELAXED, __HIP_MEMORY_SCOPE_AGENT);
    return r.v;
}
// 1 if any of the 8 bf16 halves equals the sentinel
__device__ __forceinline__ unsigned chk8(bf16x8 v) {
    union { bf16x8 v; unsigned d[4]; } u; u.v = v;
    unsigned b = 0;
#pragma unroll
    for (int i = 0; i < 4; ++i) {
        unsigned d = u.d[i] ^ 0x7FC07FC0u;
        b |= (unsigned)((d & 0xFFFFu) == 0u) | (unsigned)((d >> 16) == 0u);
    }
    return b;
}

// ---------------------------------------------------------------------------
// One-dispatch preamble: weight conversions + o-chunk sentinel fill.
__global__ void prep_kernel(const float* __restrict__ Wih0, const float* __restrict__ Wih1,
                            const float* __restrict__ Whh0, const float* __restrict__ Whh1,
                            const float* __restrict__ h0,   const float* __restrict__ Wcov,
                            u16* __restrict__ wih0b, u16* __restrict__ wih1b,
                            u16* __restrict__ whh0b, u16* __restrict__ whh1b,
                            u16* __restrict__ h0bf,  u16* __restrict__ wcovb,
                            float* __restrict__ wlastf,
                            u16* __restrict__ o0c, u16* __restrict__ o1c, int TC) {
    const int gid = blockIdx.x * 256 + threadIdx.x;
    const int gsz = gridDim.x * 256;
    for (int i = gid; i < 128; i += gsz) wlastf[i] = Wcov[i * 513 + 512];
    for (int i = gid; i < 128 * 512; i += gsz) {
        int r = i >> 9, c = i & 511;
        wcovb[i] = f2bf(Wcov[r * 513 + c]);
    }
    for (int i = gid; i < 512 * 512; i += gsz) h0bf[i] = f2bf(h0[i]);
    for (int i = gid; i < 1536 * XPK; i += gsz) {
        int r = i >> 8, c = i & 255;
        wih0b[i] = f2bf(c < 129 ? Wih0[r * 129 + c] : 0.f);
    }
    for (int i = gid; i < 1536 * 512; i += gsz) wih1b[i] = f2bf(Wih1[i]);
    for (int i = gid; i < 1536 * 512; i += gsz) whh0b[i] = f2bf(Whh0[i]);
    for (int i = gid; i < 1536 * 512; i += gsz) whh1b[i] = f2bf(Whh1[i]);
    // sentinel fill (u64 stores)
    const u64 SQ = 0x7FC07FC07FC07FC0ULL;
    const size_t nq = (size_t)TC * BT / 4;
    u64* p0 = (u64*)o0c;
    u64* p1 = (u64*)o1c;
    for (size_t i = gid; i < nq; i += gsz) p0[i] = SQ;
    for (size_t i = gid; i < nq; i += gsz) p1[i] = SQ;
}

// multi-chunk fallback: re-sentinel an o-chunk between chunks
__global__ void sentinel_kernel(u16* __restrict__ buf, int TC) {
    const u64 SQ = 0x7FC07FC07FC07FC0ULL;
    const size_t nq = (size_t)TC * BT / 4;
    u64* p = (u64*)buf;
    const size_t gid = blockIdx.x * 256 + threadIdx.x;
    const size_t gsz = (size_t)gridDim.x * 256;
    for (size_t i = gid; i < nq; i += gsz) p[i] = SQ;
}

// x: f32 [rows][129] -> bf16 [rows][256] zero-padded (shifts only)
__global__ void cvt_pad_x_kernel(const float* __restrict__ src,
                                 u16* __restrict__ dst, int rows) {
    const int n = rows * 256;
    for (int idx = blockIdx.x * blockDim.x + threadIdx.x; idx < n;
         idx += gridDim.x * blockDim.x) {
        const int row = idx >> 8, col = idx & 255;
        float v = (col < 129) ? src[(size_t)row * 129 + col] : 0.f;
        dst[idx] = f2bf(v);
    }
}

// ---------------------------------------------------------------------------
// Fused input-GEMM + GRU scan. Grid (32 col-blocks, 16 row-groups) = 512
// blocks = 2/CU. Per step: acc = xin[t]@Wih^T (register frags, pre-poll)
// + h_{t-1}@Whh^T (LDS slice, post-poll); 4-row/wave P reduce (r, z, nx, nh);
// gates; sentinel publish. AK = xin K-dim (256 for layer0, 512 for layer1).
template<int AK>
__global__ __launch_bounds__(256, 2) void scan_fused_kernel(
    const u16* __restrict__ xin,     // [TC][256][AK] bf16 (x-pad or o0)
    const u16* __restrict__ Wih,     // [1536][AK] bf16
    const float* __restrict__ bih,   // [1536] f32
    const u16* __restrict__ Whh,     // [1536][512] bf16
    const float* __restrict__ bhh,   // [1536] f32
    const int* __restrict__ lengths, // [256]
    const float* __restrict__ h0l,   // [256][512] f32 (layer slice)
    const u16* __restrict__ h0bfl,   // [256][512] bf16 (layer slice)
    u16* __restrict__ o,             // [TC][256][512]: output AND exchange
    u16* __restrict__ hcarry,        // [256][512] bf16 cross-chunk carry
    float* __restrict__ hlast,       // [256][512] f32 carry (layer slice)
    int t0, int TC) {
    __shared__ __attribute__((aligned(16))) u16 Wl[48 * 520];
    __shared__ __attribute__((aligned(16))) float P[16 * 256];
    __shared__ __attribute__((aligned(16))) float bRZ[32], bNX[16], bNH[16];
    const int tid = threadIdx.x, lane = tid & 63, w = tid >> 6;
    const int n0 = blockIdx.x * 16, b0 = blockIdx.y * 16;
    const int am = lane & 15, aq = lane >> 4;
    constexpr int KW = AK / 4;       // per-wave x K-range
    constexpr int KB2 = KW / 32;     // x kb count (2 or 4)
    // one-time: stage Whh slice into LDS (rows: 3 gates x 16 cols, K=512)
#pragma unroll
    for (int it = 0; it < 12; ++it) {
        int f = it * 2048 + tid * 8;
        int j = f >> 9, k = f & 511;
        *(short8*)&Wl[j * 520 + k] =
            *(const short8*)(Whh + ((size_t)((j >> 4) * 512 + n0 + (j & 15))) * 512 + k);
    }
    if (tid < 32) bRZ[tid] = bih[(tid >> 4) * 512 + n0 + (tid & 15)] +
                             bhh[(tid >> 4) * 512 + n0 + (tid & 15)];
    else if (tid < 48) bNX[tid - 32] = bih[1024 + n0 + (tid - 32)];
    else if (tid < 64) bNH[tid - 48] = bhh[1024 + n0 + (tid - 48)];
    // register-resident Wih fragments: 3 gates x KB2
    bf16x8 wf[3][KB2];
#pragma unroll
    for (int g = 0; g < 3; ++g)
#pragma unroll
        for (int kb = 0; kb < KB2; ++kb)
            wf[g][kb] = *(const short8*)(Wih +
                (size_t)(g * 512 + n0 + am) * AK + w * KW + kb * 32 + aq * 8);
    const int m = tid >> 4, c = tid & 15;
    const int b = b0 + m, col = n0 + c;
    float h = (t0 == 0) ? h0l[(size_t)b * 512 + col]
                        : hlast[(size_t)b * 512 + col];
    const int len = lengths[b];
    // prefetch step-0 x fragments
    bf16x8 xa[KB2];
#pragma unroll
    for (int kb = 0; kb < KB2; ++kb)
        xa[kb] = *(const short8*)(xin + (size_t)(b0 + am) * AK + w * KW + kb * 32 + aq * 8);
    __syncthreads();
    for (int tl = 0; tl < TC; ++tl) {
        const int t = t0 + tl;
        // --- x-part MFMAs (independent of the exchange; fills the wait) ---
        f32x4 ar = {}, az = {}, anx = {}, anh = {};
#pragma unroll
        for (int kb = 0; kb < KB2; ++kb) {
            ar  = __builtin_amdgcn_mfma_f32_16x16x32_bf16(xa[kb], wf[0][kb], ar, 0, 0, 0);
            az  = __builtin_amdgcn_mfma_f32_16x16x32_bf16(xa[kb], wf[1][kb], az, 0, 0, 0);
            anx = __builtin_amdgcn_mfma_f32_16x16x32_bf16(xa[kb], wf[2][kb], anx, 0, 0, 0);
        }
        // --- h exchange (sentinel-dataflow, R12) ---
        const u16* Asrc = (tl == 0) ? ((t0 == 0) ? h0bfl : hcarry)
                                    : (o + (size_t)(tl - 1) * BT);
        const u16* arow = Asrc + (size_t)(b0 + am) * 512 + w * 128 + aq * 8;
        bf16x8 av[4];
        if (tl == 0) {   // clean source (earlier dispatch), no sentinel check
            av[0] = aload16(arow);      av[1] = aload16(arow + 32);
            av[2] = aload16(arow + 64); av[3] = aload16(arow + 96);
        } else {
            for (;;) {
                av[0] = aload16(arow);
                if (!__any((int)chk8(av[0]))) break;
                __builtin_amdgcn_s_sleep(1);
            }
            for (;;) {
                av[1] = aload16(arow + 32);
                av[2] = aload16(arow + 64);
                av[3] = aload16(arow + 96);
                if (!__any((int)(chk8(av[1]) | chk8(av[2]) | chk8(av[3])))) break;
                __builtin_amdgcn_s_sleep(1);
            }
        }
        // --- h-part MFMAs ---
#pragma unroll
        for (int kb = 0; kb < 4; ++kb) {
            const int k = w * 128 + kb * 32 + aq * 8;
            bf16x8 wr = *(short8*)&Wl[(0 + am) * 520 + k];
            bf16x8 wz = *(short8*)&Wl[(16 + am) * 520 + k];
            bf16x8 wn = *(short8*)&Wl[(32 + am) * 520 + k];
            ar  = __builtin_amdgcn_mfma_f32_16x16x32_bf16(av[kb], wr, ar, 0, 0, 0);
            az  = __builtin_amdgcn_mfma_f32_16x16x32_bf16(av[kb], wz, az, 0, 0, 0);
            anh = __builtin_amdgcn_mfma_f32_16x16x32_bf16(av[kb], wn, anh, 0, 0, 0);
        }
#pragma unroll
        for (int r = 0; r < 4; ++r) {
            P[(w * 4 + 0) * 256 + (aq * 4 + r) * 16 + am] = ar[r];
            P[(w * 4 + 1) * 256 + (aq * 4 + r) * 16 + am] = az[r];
            P[(w * 4 + 2) * 256 + (aq * 4 + r) * 16 + am] = anx[r];
            P[(w * 4 + 3) * 256 + (aq * 4 + r) * 16 + am] = anh[r];
        }
        __syncthreads();                              // (A) P visible
        float Cr = bRZ[c], Cz = bRZ[16 + c], Nx = bNX[c], Nh = bNH[c];
#pragma unroll
        for (int w2 = 0; w2 < 4; ++w2) {
            Cr += P[(w2 * 4 + 0) * 256 + tid];
            Cz += P[(w2 * 4 + 1) * 256 + tid];
            Nx += P[(w2 * 4 + 2) * 256 + tid];
            Nh += P[(w2 * 4 + 3) * 256 + tid];
        }
        __syncthreads();                              // (B) P consumed; next
                                                      // write is post-barrier
        float r_ = sigm(Cr);
        float z_ = sigm(Cz);
        float n_ = tanh_f(Nx + r_ * Nh);
        float hnew = (1.f - z_) * n_ + z_ * h;
        h = (t < len) ? hnew : h;    // freeze past length
        // publish o[tl] = frozen h (output AND exchange; masked downstream)
        unsigned hb = (unsigned)f2bf(h);
        unsigned part = hb | ((unsigned)__shfl_down((int)hb, 1) << 16);
        unsigned hi2 = (unsigned)__shfl_down((int)part, 2);
        if ((lane & 3) == 0) {
            u64 q = (u64)part | ((u64)hi2 << 32);
            const int mrow = w * 4 + (lane >> 4);
            const int cg = lane & 15;      // 0,4,8,12
            __hip_atomic_store(
                (u64*)(o + (size_t)tl * BT + (size_t)(b0 + mrow) * 512 + n0 + cg),
                q, __ATOMIC_RELAXED, __HIP_MEMORY_SCOPE_AGENT);
        }
        if (tl < TC - 1) {
            // next step's x fragments: complete under the next exchange poll
#pragma unroll
            for (int kb = 0; kb < KB2; ++kb)
                xa[kb] = *(const short8*)(xin +
                    ((size_t)(tl + 1) * 256 + b0 + am) * AK + w * KW + kb * 32 + aq * 8);
        } else {
            // cross-chunk / cross-launch carries (plain stores, stream order)
            hcarry[(size_t)b * 512 + col] = f2bf(h);
            hlast[(size_t)b * 512 + col] = h;
        }
    }
}

// ---------------------------------------------------------------------------
// preds as a 128x128 GEMM (N=128 -> one col-block) with fused epilogue:
// out[b][t][c] = mask * (acc + b_cov[c] + x[t,b,0]*wlast[c]); channel 128
// zeroed. o1c rows past len hold frozen h; the t < len-1 mask here matches
// the reference, so outputs are identical. 2-phase dbuf staging.
__global__ __launch_bounds__(256) void preds_kernel(
    const u16* __restrict__ o1c, const u16* __restrict__ WcovBf,
    const float* __restrict__ wlastf, const float* __restrict__ bcov,
    const float* __restrict__ x, const int* __restrict__ lengths,
    float* __restrict__ out, int t0) {
    __shared__ __attribute__((aligned(16))) u16 Sh[2][16384];
    const int tid = threadIdx.x, lane = tid & 63, w = tid >> 6;
    const int m0 = blockIdx.x * 128;
    const int r0 = (w & 1) * 64, c0 = (w >> 1) * 64;
    const int am = lane & 15, aq = lane >> 4;
    const int l8 = lane >> 3, lc = lane & 7;
    const int swz = (lc ^ l8) << 3;
    f32x4 acc[4][4] = {};
#pragma unroll
    for (int s = 0; s < 4; ++s) {
        const int i = w * 4 + s, row = i * 8 + l8;
        GLD16(o1c + (size_t)(m0 + row) * 512 + swz, &Sh[0][i * 512]);
        GLD16(WcovBf + (size_t)row * 512 + swz, &Sh[0][8192 + i * 512]);
    }
    __syncthreads();
    int cur = 0;
    for (int kt = 0; kt < 8; ++kt) {
        if (kt + 1 < 8) {
            const int kb = (kt + 1) << 6;
#pragma unroll
            for (int s = 0; s < 4; ++s) {
                const int i = w * 4 + s, row = i * 8 + l8;
                GLD16(o1c + (size_t)(m0 + row) * 512 + kb + swz,
                      &Sh[cur ^ 1][i * 512]);
                GLD16(WcovBf + (size_t)row * 512 + kb + swz,
                      &Sh[cur ^ 1][8192 + i * 512]);
            }
        }
        const u16* Ash = &Sh[cur][0];
        const u16* Bsh = &Sh[cur][8192];
#pragma unroll
        for (int ks = 0; ks < 2; ++ks) {
            bf16x8 a[4], bb[4];
#pragma unroll
            for (int f = 0; f < 4; ++f) {
                const int ar2 = r0 + f * 16 + am;
                a[f] = *(short8*)&Ash[ar2 * 64 + (((ks * 4 + aq) ^ (ar2 & 7)) << 3)];
            }
#pragma unroll
            for (int f = 0; f < 4; ++f) {
                const int br = c0 + f * 16 + am;
                bb[f] = *(short8*)&Bsh[br * 64 + (((ks * 4 + aq) ^ (br & 7)) << 3)];
            }
#pragma unroll
            for (int fi = 0; fi < 4; ++fi)
#pragma unroll
                for (int fj = 0; fj < 4; ++fj)
                    acc[fi][fj] = __builtin_amdgcn_mfma_f32_16x16x32_bf16(
                        a[fi], bb[fj], acc[fi][fj], 0, 0, 0);
        }
        __syncthreads();
        cur ^= 1;
    }
    const int tl = m0 >> 8;     // one tl per block (128 rows = half of a tl)
    const int t = t0 + tl;
    if (t < 511) {
#pragma unroll
        for (int fj = 0; fj < 4; ++fj) {
            const int cc = c0 + fj * 16 + am;
            const float bc = bcov[cc], wl = wlastf[cc];
#pragma unroll
            for (int fi = 0; fi < 4; ++fi) {
#pragma unroll
                for (int r = 0; r < 4; ++r) {
                    const int row = m0 + r0 + fi * 16 + aq * 4 + r;
                    const int b = row & 255;
                    const bool valid = t < lengths[b] - 1;
                    const float tim = x[(size_t)t * (256 * 129) + b * 129];
                    out[(size_t)b * (511 * 129) + (size_t)t * 129 + cc] =
                        valid ? acc[fi][fj][r] + bc + tim * wl : 0.f;
                }
            }
        }
        if (tid < 128)  // channel 128 is always zero
            out[(size_t)((m0 & 255) + tid) * (511 * 129) + (size_t)t * 129 + 128] = 0.f;
    }
}

// ---------------------------------------------------------------------------
// dist[i][p] = exp(-(last_flat[i] @ W_par[p] + b_par[p])), f32 out.
__global__ void dist_kernel(const float* __restrict__ hl0,
                            const float* __restrict__ hl1,
                            const float* __restrict__ Wpar,
                            const float* __restrict__ bpar, float* __restrict__ out) {
    const int w = threadIdx.x >> 6, lane = threadIdx.x & 63;
    const float bp0 = bpar[0], bp1 = bpar[1];
    for (int rr = 0; rr < 8; ++rr) {
        const int i = (blockIdx.x * 4 + w) * 8 + rr;
        const int l = i >> 7, bb = (2 * i) & 255;
        const float* base = (l ? hl1 : hl0) + (size_t)bb * 512;
        float a0 = 0.f, a1 = 0.f;
#pragma unroll
        for (int cc = 0; cc < 16; ++cc) {
            const int k = cc * 64 + lane;
            const float v = base[k];
            a0 += v * Wpar[k];
            a1 += v * Wpar[1024 + k];
        }
#pragma unroll
        for (int off = 32; off; off >>= 1) {
            a0 += __shfl_down(a0, off);
            a1 += __shfl_down(a1, off);
        }
        if (lane == 0) {
            out[PRED_ELEMS + i * 2 + 0] = __expf(-(a0 + bp0));
            out[PRED_ELEMS + i * 2 + 1] = __expf(-(a1 + bp1));
        }
    }
}

// ---------------------------------------------------------------------------
extern "C" void kernel_launch(void* const* d_in, const int* in_sizes, int n_in,
                              void* d_out, int out_size, void* d_ws, size_t ws_size,
                              hipStream_t stream) {
    const float* x    = (const float*)d_in[0];
    const int* lens   = (const int*)d_in[1];
    const float* h0   = (const float*)d_in[2];
    const float* Wih0 = (const float*)d_in[3];
    const float* Whh0 = (const float*)d_in[4];
    const float* bih0 = (const float*)d_in[5];
    const float* bhh0 = (const float*)d_in[6];
    const float* Wih1 = (const float*)d_in[7];
    const float* Whh1 = (const float*)d_in[8];
    const float* bih1 = (const float*)d_in[9];
    const float* bhh1 = (const float*)d_in[10];
    const float* Wcov = (const float*)d_in[11];
    const float* bcov = (const float*)d_in[12];
    const float* Wpar = (const float*)d_in[13];
    const float* bpar = (const float*)d_in[14];
    float* out = (float*)d_out;
    char* wsb = (char*)d_ws;

    size_t off = 0;
    auto take = [&](size_t bytes) -> size_t {
        size_t r = off; off += (bytes + 255) & ~(size_t)255; return r;
    };
    const size_t oHl0   = take((size_t)BT * 4);         // layer0 f32 carry
    const size_t oHl1   = take((size_t)BT * 4);         // layer1 f32 carry
    const size_t oHc0   = take((size_t)BT * 2);         // layer0 bf16 chunk carry
    const size_t oHc1   = take((size_t)BT * 2);         // layer1 bf16 chunk carry
    const size_t oH0bf  = take((size_t)2 * BT * 2);     // bf16(h0) both layers
    const size_t oWih0b = take((size_t)G3H * XPK * 2);
    const size_t oWih1b = take((size_t)G3H * 512 * 2);
    const size_t oWhh0b = take((size_t)G3H * 512 * 2);
    const size_t oWhh1b = take((size_t)G3H * 512 * 2);
    const size_t oWcovb = take((size_t)128 * 512 * 2);
    const size_t oWlast = take(512);
    const size_t fixed = off;

    const size_t per = (size_t)256 * XPK * 2 +          // xbf chunk row
                       2 * (size_t)256 * 512 * 2 + 2048; // o0 + o1
    const size_t remain = ws_size > fixed ? ws_size - fixed : 0;
    int TC = 1;
    const int cands[10] = {512, 256, 128, 64, 32, 16, 8, 4, 2, 1};
    for (int i = 0; i < 10; ++i)
        if ((size_t)cands[i] * per <= remain) { TC = cands[i]; break; }

    const size_t oXbf = take((size_t)TC * 256 * XPK * 2);
    const size_t oO0  = take((size_t)TC * 256 * 512 * 2);
    const size_t oO1  = take((size_t)TC * 256 * 512 * 2);

    float* hl0  = (float*)(wsb + oHl0);
    float* hl1  = (float*)(wsb + oHl1);
    u16* hcar0  = (u16*)(wsb + oHc0);
    u16* hcar1  = (u16*)(wsb + oHc1);
    u16* h0bf   = (u16*)(wsb + oH0bf);
    u16* wih0b  = (u16*)(wsb + oWih0b);
    u16* wih1b  = (u16*)(wsb + oWih1b);
    u16* whh0b  = (u16*)(wsb + oWhh0b);
    u16* whh1b  = (u16*)(wsb + oWhh1b);
    u16* wcovb  = (u16*)(wsb + oWcovb);
    float* wlastf = (float*)(wsb + oWlast);
    u16* xbfc   = (u16*)(wsb + oXbf);
    u16* o0c    = (u16*)(wsb + oO0);
    u16* o1c    = (u16*)(wsb + oO1);

    prep_kernel<<<1024, 256, 0, stream>>>(Wih0, Wih1, Whh0, Whh1, h0, Wcov,
                                          wih0b, wih1b, whh0b, whh1b, h0bf,
                                          wcovb, wlastf, o0c, o1c, TC);

    for (int t0 = 0; t0 < T_DIM; t0 += TC) {
        int n = TC * 256 * XPK;
        int pg = (n + 255) / 256; if (pg > 2048) pg = 2048;
        cvt_pad_x_kernel<<<pg, 256, 0, stream>>>(
            x + (size_t)t0 * 256 * 129, xbfc, TC * 256);
        if (t0 > 0)   // multi-chunk fallback: re-arm sentinels
            sentinel_kernel<<<2048, 256, 0, stream>>>(o0c, TC);
        scan_fused_kernel<XPK><<<dim3(32, 16), 256, 0, stream>>>(
            xbfc, wih0b, bih0, whh0b, bhh0, lens, h0, h0bf,
            o0c, hcar0, hl0, t0, TC);
        if (t0 > 0)
            sentinel_kernel<<<2048, 256, 0, stream>>>(o1c, TC);
        scan_fused_kernel<512><<<dim3(32, 16), 256, 0, stream>>>(
            o0c, wih1b, bih1, whh1b, bhh1, lens, h0 + (size_t)BT,
            h0bf + (size_t)BT, o1c, hcar1, hl1, t0, TC);
        preds_kernel<<<dim3(TC * 2), 256, 0, stream>>>(
            o1c, wcovb, wlastf, bcov, x, lens, out, t0);
    }
    dist_kernel<<<8, 256, 0, stream>>>(hl0, hl1, Wpar, bpar, out);
}